// Round 5
// baseline (574.551 us; speedup 1.0000x reference)
//
#include <hip/hip_runtime.h>
#include <hip/hip_bf16.h>
#include <math.h>

// Problem shape (fixed): B=4, S=1024, D=768, A=192, H=3, hd=64
#define BDIM 4
#define SDIM 1024
#define DDIM 768
#define ADIM 192
#define HDIM 3
#define HD   64
#define MROWS (BDIM*SDIM)      // 4096
#define NCHUNK (SDIM/32)       // 32
#define EPSLN 1e-6f

// ---------------- DPP wave reduction (64-lane sum, result broadcast) -------
template<int CTRL, int RMASK, bool BC>
__device__ __forceinline__ float dpp_add_step(float x) {
    int t = __builtin_amdgcn_update_dpp(0, __float_as_int(x), CTRL, RMASK, 0xf, BC);
    return x + __int_as_float(t);
}
__device__ __forceinline__ float wave_bcast_sum(float x) {
    x = dpp_add_step<0x111, 0xf, true >(x);
    x = dpp_add_step<0x112, 0xf, true >(x);
    x = dpp_add_step<0x114, 0xf, true >(x);
    x = dpp_add_step<0x118, 0xf, true >(x);
    x = dpp_add_step<0x142, 0xa, false>(x);
    x = dpp_add_step<0x143, 0xc, false>(x);
    return __int_as_float(__builtin_amdgcn_readlane(__float_as_int(x), 63));
}
__device__ __forceinline__ float rl(float v, int lane) {
    return __int_as_float(__builtin_amdgcn_readlane(__float_as_int(v), lane));
}
__device__ __forceinline__ float fast_rsq(float x) {
    float r;
    asm("v_rsq_f32 %0, %1" : "=v"(r) : "v"(x));
    return r;
}
// 5 simultaneous 64-lane sums via fused DPP adds (validated r7-r10).
__device__ __forceinline__ void red5_asm(float& a, float& b, float& c,
                                         float& d, float& e) {
#define R5_SHR(N)                                                              \
    asm("v_add_f32 %0, %0, %0 row_shr:" #N " row_mask:0xf bank_mask:0xf bound_ctrl:0" : "+v"(a)); \
    asm("v_add_f32 %0, %0, %0 row_shr:" #N " row_mask:0xf bank_mask:0xf bound_ctrl:0" : "+v"(b)); \
    asm("v_add_f32 %0, %0, %0 row_shr:" #N " row_mask:0xf bank_mask:0xf bound_ctrl:0" : "+v"(c)); \
    asm("v_add_f32 %0, %0, %0 row_shr:" #N " row_mask:0xf bank_mask:0xf bound_ctrl:0" : "+v"(d)); \
    asm("v_add_f32 %0, %0, %0 row_shr:" #N " row_mask:0xf bank_mask:0xf bound_ctrl:0" : "+v"(e));
#define R5_BC(N, RM)                                                           \
    asm("v_add_f32 %0, %0, %0 row_bcast:" #N " row_mask:" #RM " bank_mask:0xf" : "+v"(a)); \
    asm("v_add_f32 %0, %0, %0 row_bcast:" #N " row_mask:" #RM " bank_mask:0xf" : "+v"(b)); \
    asm("v_add_f32 %0, %0, %0 row_bcast:" #N " row_mask:" #RM " bank_mask:0xf" : "+v"(c)); \
    asm("v_add_f32 %0, %0, %0 row_bcast:" #N " row_mask:" #RM " bank_mask:0xf" : "+v"(d)); \
    asm("v_add_f32 %0, %0, %0 row_bcast:" #N " row_mask:" #RM " bank_mask:0xf" : "+v"(e));
    R5_SHR(1) R5_SHR(2) R5_SHR(4) R5_SHR(8)
    R5_BC(15, 0xa) R5_BC(31, 0xc)
#undef R5_SHR
#undef R5_BC
}

// ---------------- per-row LayerNorm stats: (mu, rstd) over 192 -------------
__global__ __launch_bounds__(64) void lnstats(
    const float* __restrict__ in, float2* __restrict__ st)
{
    int row = blockIdx.x, tid = threadIdx.x;
    float x0 = in[(size_t)row * ADIM + tid];
    float x1 = in[(size_t)row * ADIM + 64 + tid];
    float x2 = in[(size_t)row * ADIM + 128 + tid];
    float s1 = wave_bcast_sum((x0 + x1) + x2);
    float s2 = wave_bcast_sum(fmaf(x0, x0, fmaf(x1, x1, x2 * x2)));
    if (tid == 0) {
        float mu = s1 * (1.f / 192.f);
        float var = s2 * (1.f / 192.f) - mu * mu;
        st[row] = make_float2(mu, rsqrtf(var + EPSLN));
    }
}

// ---------------- Generic fp32 tiled GEMM: C = act(lnA(A)@B + bias) --------
template<int ACT, int LAYOUT, int LNA>
__global__ __launch_bounds__(256) void gemm_k(
    const float* __restrict__ A, const float* __restrict__ Bm,
    const float* __restrict__ bias, float* __restrict__ C,
    int M, int N, int K,
    const float2* __restrict__ lnst, const float* __restrict__ lng,
    const float* __restrict__ lnbb)
{
    __shared__ float As[16][68];
    __shared__ float Bs[16][68];
    const int tid = threadIdx.x;
    const int bm = blockIdx.y * 64, bn = blockIdx.x * 64;
    const int tr = tid >> 4, tc = tid & 15;
    float acc[4][4] = {};

    for (int k0 = 0; k0 < K; k0 += 16) {
        #pragma unroll
        for (int p = 0; p < 4; ++p) {
            int m = (tid >> 4) + p * 16;
            int kk = tid & 15;
            float av = A[(size_t)(bm + m) * K + k0 + kk];
            if (LNA) {
                float2 stv = lnst[bm + m];
                av = fmaf((av - stv.x) * stv.y, lng[k0 + kk], lnbb[k0 + kk]);
            }
            As[kk][m] = av;
        }
        #pragma unroll
        for (int p = 0; p < 4; ++p) {
            int kk = (tid >> 6) + p * 4;
            int n = tid & 63;
            Bs[kk][n] = Bm[(size_t)(k0 + kk) * N + bn + n];
        }
        __syncthreads();
        #pragma unroll
        for (int kk = 0; kk < 16; ++kk) {
            // 16B-aligned: As row stride 272B, offsets are multiples of 16B
            const float4 a4 = *(const float4*)&As[kk][tr * 4];
            const float4 b4 = *(const float4*)&Bs[kk][tc * 4];
            float aa[4] = {a4.x, a4.y, a4.z, a4.w};
            float bb[4] = {b4.x, b4.y, b4.z, b4.w};
            #pragma unroll
            for (int i = 0; i < 4; ++i)
                #pragma unroll
                for (int j = 0; j < 4; ++j)
                    acc[i][j] = fmaf(aa[i], bb[j], acc[i][j]);
        }
        __syncthreads();
    }

    #pragma unroll
    for (int i = 0; i < 4; ++i) {
        int m = bm + tr * 4 + i;
        #pragma unroll
        for (int j = 0; j < 4; ++j) {
            int n = bn + tc * 4 + j;
            float v = acc[i][j];
            if (bias) v += bias[n];
            if (ACT == 1) v = v / (1.f + __expf(-v));   // silu
            if (LAYOUT == 0) {
                C[(size_t)m * N + n] = v;
            } else {
                int b  = m >> 10, s = m & 1023;
                int hh = n >> 6,  d = n & 63;
                C[(((size_t)b * HDIM + hh) * SDIM + s) * HD + d] = v;
            }
        }
    }
}

// ---------------- fused QKV GEMM: one launch, blockIdx.z picks the head ----
__global__ __launch_bounds__(256) void gemm_qkv(
    const float* __restrict__ A, const float* __restrict__ BWq,
    const float* __restrict__ BWk, const float* __restrict__ BWv,
    float* __restrict__ Cbase)
{
    const float* Bm = (blockIdx.z == 0) ? BWq : (blockIdx.z == 1) ? BWk : BWv;
    float* C = Cbase + (size_t)blockIdx.z * ((size_t)MROWS * ADIM);
    __shared__ float As[16][68];
    __shared__ float Bs[16][68];
    const int tid = threadIdx.x;
    const int bm = blockIdx.y * 64, bn = blockIdx.x * 64;
    const int tr = tid >> 4, tc = tid & 15;
    float acc[4][4] = {};

    for (int k0 = 0; k0 < ADIM; k0 += 16) {
        #pragma unroll
        for (int p = 0; p < 4; ++p) {
            int m = (tid >> 4) + p * 16;
            int kk = tid & 15;
            As[kk][m] = A[(size_t)(bm + m) * ADIM + k0 + kk];
        }
        #pragma unroll
        for (int p = 0; p < 4; ++p) {
            int kk = (tid >> 6) + p * 4;
            int n = tid & 63;
            Bs[kk][n] = Bm[(size_t)(k0 + kk) * ADIM + bn + n];
        }
        __syncthreads();
        #pragma unroll
        for (int kk = 0; kk < 16; ++kk) {
            const float4 a4 = *(const float4*)&As[kk][tr * 4];
            const float4 b4 = *(const float4*)&Bs[kk][tc * 4];
            float aa[4] = {a4.x, a4.y, a4.z, a4.w};
            float bb[4] = {b4.x, b4.y, b4.z, b4.w};
            #pragma unroll
            for (int i = 0; i < 4; ++i)
                #pragma unroll
                for (int j = 0; j < 4; ++j)
                    acc[i][j] = fmaf(aa[i], bb[j], acc[i][j]);
        }
        __syncthreads();
    }

    #pragma unroll
    for (int i = 0; i < 4; ++i) {
        int m = bm + tr * 4 + i;
        #pragma unroll
        for (int j = 0; j < 4; ++j) {
            int n = bn + tc * 4 + j;
            int b  = m >> 10, s = m & 1023;
            int hh = n >> 6,  d = n & 63;
            C[(((size_t)b * HDIM + hh) * SDIM + s) * HD + d] = acc[i][j];
        }
    }
}

// ------- eta = sigmoid(h @ lr_w + lr_b)/(64*64) -> er6b[.].x ---------------
// (folds the staging-time extra 1/64 that ttt_scan's TOK formula expects)
__global__ __launch_bounds__(192) void eta_kernel(
    const float* __restrict__ h, const float* __restrict__ lr_w,
    const float* __restrict__ lr_b, float2* __restrict__ er6b)
{
    const int row = blockIdx.x, tid = threadIdx.x, wave = tid >> 6;
    __shared__ float part[3][3];   // [wave][hh]
    float hv = h[(size_t)row * ADIM + tid];
    float p0 = hv * lr_w[tid * 3 + 0];
    float p1 = hv * lr_w[tid * 3 + 1];
    float p2 = hv * lr_w[tid * 3 + 2];
    float s0 = wave_bcast_sum(p0);
    float s1 = wave_bcast_sum(p1);
    float s2 = wave_bcast_sum(p2);
    if ((tid & 63) == 0) {
        part[wave][0] = s0; part[wave][1] = s1; part[wave][2] = s2;
    }
    __syncthreads();
    if (tid < 3) {
        float acc = (part[0][tid] + part[1][tid]) + part[2][tid] + lr_b[tid];
        float e = 1.f / (1.f + __expf(-acc)) * (1.f / 4096.f);
        int b = row >> 10, s = row & 1023;
        er6b[(size_t)(b * HDIM + tid) * SDIM + s].x = e;
    }
}

// -- pre: A=[k.k+1], B=[q.k+1], a-vectors (into vb), r6 -> er6b[.].y ---------
__global__ __launch_bounds__(256) void ab_kernel(
    const float* __restrict__ qb, const float* __restrict__ kb,
    float* __restrict__ vb,            // in: v; out: a = (bw-(v-k))*gw
    const float* __restrict__ ttt_g, const float* __restrict__ ttt_b,
    float* __restrict__ Ab, float* __restrict__ Bb,
    float2* __restrict__ er6b)
{
    int bh = blockIdx.x >> 5, c = blockIdx.x & 31, cs = c * 32;
    int hh = bh % HDIM;
    __shared__ float Kc[32][65], Qc[32][65], Vc[32][65];
    for (int i = threadIdx.x; i < 2048; i += 256) {
        int t = i >> 6, j = i & 63;
        Kc[t][j] = kb[((size_t)bh * SDIM + cs + t) * HD + j];
        Qc[t][j] = qb[((size_t)bh * SDIM + cs + t) * HD + j];
        Vc[t][j] = vb[((size_t)bh * SDIM + cs + t) * HD + j];
    }
    __syncthreads();
    size_t base = ((size_t)(bh * NCHUNK + c)) * 1024;
    for (int e = threadIdx.x; e < 1024; e += 256) {
        int t = e >> 5, s = e & 31;
        float a = 1.f, b = 1.f;
        #pragma unroll
        for (int j = 0; j < 64; ++j) {
            float ks = Kc[s][j];
            a = fmaf(Kc[t][j], ks, a);
            b = fmaf(Qc[t][j], ks, b);
        }
        Ab[base + e] = a;
        Bb[base + e] = b;
    }
    for (int i = threadIdx.x; i < 2048; i += 256) {
        int t = i >> 6, j = i & 63;
        float gwv = ttt_g[hh * 64 + j], bwv = ttt_b[hh * 64 + j];
        float av = fmaf(-(Vc[t][j] - Kc[t][j]), gwv, bwv * gwv);
        Vc[t][j] = av;
        vb[((size_t)bh * SDIM + cs + t) * HD + j] = av;
    }
    __syncthreads();
    if (threadIdx.x < 32) {
        int t = threadIdx.x;
        float acc = 0.f;
        #pragma unroll
        for (int j = 0; j < 64; ++j) acc += Vc[t][j];
        er6b[(size_t)bh * SDIM + cs + t].y = acc;
    }
}

// ---------------- staging helper (global -> LDS, float4): K and A only -----
__device__ __forceinline__ void stage_chunk(
    int pp, int cc, int bh, int idx, int nth,
    const float* __restrict__ kbuf, const float* __restrict__ Ab,
    float4* K4, float4* A4)
{
    const float4* kg = (const float4*)(kbuf + ((size_t)bh * SDIM + cc * 32) * HD);
    const float4* Ag = (const float4*)(Ab + ((size_t)(bh * NCHUNK + cc)) * 1024);
    for (int i = idx; i < 512; i += nth) K4[pp * 512 + i] = kg[i];
    for (int i = idx; i < 256; i += nth) A4[pp * 256 + i] = Ag[i];
}

// ---------------- the sequential TTT scan (12 blocks) ----------------------
// r15 = r14 (merged 32-token serial pass) with the register-pressure fix:
// the A-row double-buffer (avA/avB, 16 float4 = 64 VGPR live across every
// token) is replaced by TRANSIENT per-token loads: at the top of TOK(I),
// load only row I's needed float4s (q=(I+1)>>2 .. 7, compile-time offsets)
// into a token-local av[8]. Live range = within one token; LDS latency
// (~120cy) hides under red5+LN chain (~200cy). Peak live regs ~106 vs
// r14's ~144-needed/112-allocated (which forced spills/load-sinking into
// the serial dependency chain = the 115us regression vs r10).
__global__ __launch_bounds__(256, 1) void ttt_scan(
    const float* __restrict__ kbuf, const float* __restrict__ abuf,
    const float2* __restrict__ er6b, const float* __restrict__ Ab,
    const float* __restrict__ W1,   const float* __restrict__ b1,
    const float* __restrict__ ttt_g, const float* __restrict__ ttt_b,
    float* __restrict__ Gbuf, float* __restrict__ W0save, float* __restrict__ b0save)
{
    const int bh = blockIdx.x, hh = bh % HDIM;
    const int tid = threadIdx.x, lane = tid & 63;
    const int wv = tid >> 6;
    __shared__ float  Zp[3][32][64];   // 24 KB: waves 1-3 Z0 partials
    __shared__ float4 K4s[2 * 512];    // 16 KB: K double-buffered
    __shared__ float4 A4s[2 * 256];    //  8 KB: A double-buffered
    __shared__ float  Gl[32][64];      //  8 KB: per-token eta*g (full chunk)

    float Wreg[16];
    #pragma unroll
    for (int r = 0; r < 16; ++r)
        Wreg[r] = W1[hh * 4096 + (wv * 16 + r) * 64 + lane];
    float breg = b1[hh * 64 + lane];
    const float gw = ttt_g[hh * 64 + lane];
    const float bw = ttt_b[hh * 64 + lane];
    const float w3 = gw * gw;
    (void)bw;
    const float Cg2 = wave_bcast_sum(w3);

    stage_chunk(0, 0, bh, tid, 256, kbuf, Ab, K4s, A4s);
    __syncthreads();

    for (int c = 0; c < NCHUNK; ++c) {
        const int cs = c * 32;
        const int p = c & 1;
        const float*  ag = abuf + ((size_t)bh * SDIM + cs) * HD;
        const float2* eg = er6b + (size_t)bh * SDIM + cs;

        {
            float* Wd = W0save + ((size_t)(bh * NCHUNK + c)) * 4096
                        + (wv * 16) * 64 + lane;
            #pragma unroll
            for (int r = 0; r < 16; ++r) Wd[r * 64] = Wreg[r];
            if (tid < 64) b0save[(bh * NCHUNK + c) * 64 + tid] = breg;
        }

        // ---- wave 0: issue 4-token-deep a/er prefetch before P1 ----------
        float a0, a1, a2, a3;
        float2 e0, e1, e2, e3;
        if (wv == 0) {
            a0 = ag[lane];          e0 = eg[0];
            a1 = ag[HD + lane];     e1 = eg[1];
            a2 = ag[2 * HD + lane]; e2 = eg[2];
            a3 = ag[3 * HD + lane]; e3 = eg[3];
        }

        // ---- P1 (all waves): Z0 partials for all 32 tokens ---------------
        float Z[32];
        #pragma unroll
        for (int i = 0; i < 32; ++i) {
            float zt = 0.f;
            #pragma unroll
            for (int r4 = 0; r4 < 4; ++r4) {
                const float4 kv = K4s[p * 512 + i * 16 + wv * 4 + r4];
                zt = fmaf(kv.x, Wreg[r4 * 4 + 0], zt);
                zt = fmaf(kv.y, Wreg[r4 * 4 + 1], zt);
                zt = fmaf(kv.z, Wreg[r4 * 4 + 2], zt);
                zt = fmaf(kv.w, Wreg[r4 * 4 + 3], zt);
            }
            if (wv != 0) Zp[wv - 1][i][lane] = (wv == 1) ? zt + breg : zt;
            else         Z[i] = zt;
        }
        __syncthreads();   // (A) Zp ready; buffer p staged

        // ---- P2: wave 0 serial over 32 tokens; waves 1-3 stage next ------
        if (wv == 0) {
            __builtin_amdgcn_s_setprio(1);
            #pragma unroll
            for (int i = 0; i < 32; ++i)
                Z[i] = ((Z[i] + Zp[0][i][lane]) +
                        (Zp[1][i][lane] + Zp[2][i][lane]));
#define TOK(I, aS, erS)                                                        \
    {                                                                          \
        float a  = aS;                                                         \
        float2 er = erS;                                                       \
        if ((I) < 28) {                                                        \
            aS  = ag[((I) + 4) * HD + lane];                                   \
            erS = eg[(I) + 4];                                                 \
        }                                                                      \
        float4 av[8];                                                          \
        _Pragma("unroll")                                                      \
        for (int q = ((I) + 1) >> 2; q < 8; ++q)                               \
            av[q] = A4s[p * 256 + (I) * 8 + q];                                \
        float z  = Z[I];                                                       \
        float zg = z * w3;                                                     \
        float x1 = z, x2 = z * z, x3 = zg, x4 = zg * z, x5 = z * a;            \
        red5_asm(x1, x2, x3, x4, x5);                                          \
        float r1 = rl(x1, 63), r2 = rl(x2, 63), r3 = rl(x3, 63);               \
        float r4 = rl(x4, 63), r5 = rl(x5, 63);                                \
        float r6t = er.y;                                                      \
        float mu   = r1 * (1.f / 64.f);                                        \
        float var  = fmaf(-mu, mu, r2 * (1.f / 64.f));                         \
        float rstd = fast_rsq(var + EPSLN);                                    \
        float mc   = mu * Cg2;                                                 \
        float sgxh = fmaf(rstd, r3 - mc, r6t);                                 \
        float t4v  = fmaf(mu, mc, fmaf(-2.f * mu, r3, r4));                    \
        float sgz  = fmaf(rstd * rstd, t4v, rstd * (r5 - mu * r6t));           \
        float zh   = (z - mu) * rstd;                                          \
        float gxh  = fmaf(zh, w3, a);                                          \
        float ge   = (fmaf(64.f, gxh, -sgxh) - zh * sgz) * (rstd * er.x);      \
        Gl[I][lane] = ge;                                                      \
        _Pragma("unroll")                                                      \
        for (int u = (I) + 1; u < 32; ++u) {                                   \
            const float4 c4 = av[(u) >> 2]; const int m4 = (u) & 3;            \
            float Atu = (m4 == 0) ? c4.x : (m4 == 1) ? c4.y                    \
                      : (m4 == 2) ? c4.z : c4.w;                               \
            Z[u] = fmaf(-Atu, ge, Z[u]);                                       \
        }                                                                      \
    }
            #pragma unroll
            for (int tp = 0; tp < 8; ++tp) {
                TOK(4 * tp + 0, a0, e0)
                TOK(4 * tp + 1, a1, e1)
                TOK(4 * tp + 2, a2, e2)
                TOK(4 * tp + 3, a3, e3)
            }
#undef TOK
            __builtin_amdgcn_s_setprio(0);
        } else if (c < NCHUNK - 1) {
            stage_chunk(p ^ 1, c + 1, bh, tid - 64, 192, kbuf, Ab, K4s, A4s);
        }
        __syncthreads();   // (B) Gl ready; staging done

        // ---- P3 (all waves): W -= K^T@G ; b -= colsum(G); Gbuf -----------
        float btot = 0.f;
        #pragma unroll
        for (int s = 0; s < 32; ++s) {
            float gd = Gl[s][lane];
            btot += gd;
            #pragma unroll
            for (int r4 = 0; r4 < 4; ++r4) {
                const float4 kv = K4s[p * 512 + s * 16 + wv * 4 + r4];
                Wreg[r4 * 4 + 0] = fmaf(-kv.x, gd, Wreg[r4 * 4 + 0]);
                Wreg[r4 * 4 + 1] = fmaf(-kv.y, gd, Wreg[r4 * 4 + 1]);
                Wreg[r4 * 4 + 2] = fmaf(-kv.z, gd, Wreg[r4 * 4 + 2]);
                Wreg[r4 * 4 + 3] = fmaf(-kv.w, gd, Wreg[r4 * 4 + 3]);
            }
        }
        breg -= btot;
        {
            float* gb = Gbuf + ((size_t)bh * SDIM + cs) * HD + lane;
            #pragma unroll
            for (int r = 0; r < 8; ++r)
                gb[(wv * 8 + r) * HD] = Gl[wv * 8 + r][lane];
        }
    }
}

// ---------------- post: Zq = Qc@W0 + b0 - tril(B)@G ; ys = q + ln(Zq) ------
__global__ __launch_bounds__(256) void post_kernel(
    const float* __restrict__ qbuf, const float* __restrict__ Bb,
    const float* __restrict__ Gbuf, const float* __restrict__ W0save,
    const float* __restrict__ b0save,
    const float* __restrict__ ttt_g, const float* __restrict__ ttt_b,
    float* __restrict__ ys)
{
    const int bh = blockIdx.x >> 5, c = blockIdx.x & 31, cs = c * 32;
    const int b = bh / HDIM, hh = bh % HDIM;
    const int tid = threadIdx.x, lane = tid & 63, wave = tid >> 6;
    __shared__ float Qc[32][65];
    __shared__ float W0l[64][65];
    __shared__ float Gl[32][64];
    for (int i = tid; i < 2048; i += 256) {
        int t = i >> 6, j = i & 63;
        Qc[t][j] = qbuf[((size_t)bh * SDIM + cs + t) * HD + j];
        Gl[t][j] = Gbuf[((size_t)bh * SDIM + cs + t) * HD + j];
    }
    for (int i = tid; i < 4096; i += 256)
        W0l[i >> 6][i & 63] = W0save[((size_t)(bh * NCHUNK + c)) * 4096 + i];
    __syncthreads();

    const float bb0 = b0save[(bh * NCHUNK + c) * 64 + lane];
    const float gw = ttt_g[hh * 64 + lane], bw = ttt_b[hh * 64 + lane];
    float acc[8];
    #pragma unroll
    for (int r = 0; r < 8; ++r) acc[r] = bb0;
    for (int j = 0; j < 64; ++j) {
        float w0 = W0l[j][lane];
        #pragma unroll
        for (int r = 0; r < 8; ++r)
            acc[r] = fmaf(Qc[wave * 8 + r][j], w0, acc[r]);
    }
    float Breg[8];
    size_t bbase = ((size_t)(bh * NCHUNK + c)) * 1024;
    #pragma unroll
    for (int r = 0; r < 8; ++r)
        Breg[r] = Bb[bbase + (wave * 8 + r) * 32 + (lane & 31)];
    #pragma unroll
    for (int s = 0; s < 32; ++s) {
        float gd = Gl[s][lane];
        #pragma unroll
        for (int r = 0; r < 8; ++r) {
            int t = wave * 8 + r;
            float Bts = rl(Breg[r], s);
            acc[r] = (s <= t) ? fmaf(-Bts, gd, acc[r]) : acc[r];
        }
    }
    #pragma unroll
    for (int r = 0; r < 8; ++r) {
        int t = wave * 8 + r;
        float s1 = wave_bcast_sum(acc[r]);
        float s2 = wave_bcast_sum(acc[r] * acc[r]);
        float mu = s1 * (1.f / 64.f);
        float var = s2 * (1.f / 64.f) - mu * mu;
        float rstd = rsqrtf(var + EPSLN);
        float zh = (acc[r] - mu) * rstd;
        float val = zh * gw + bw + Qc[t][lane];
        ys[((size_t)(b * SDIM) + cs + t) * ADIM + hh * HD + lane] = val;
    }
}

// ---------------- launch ---------------------------------------------------
extern "C" void kernel_launch(void* const* d_in, const int* in_sizes, int n_in,
                              void* d_out, int out_size, void* d_ws, size_t ws_size,
                              hipStream_t stream)
{
    const float* x      = (const float*)d_in[0];
    const float* W_down = (const float*)d_in[1];
    const float* b_down = (const float*)d_in[2];
    const float* Wq     = (const float*)d_in[3];
    const float* Wk     = (const float*)d_in[4];
    const float* Wv     = (const float*)d_in[5];
    const float* Wo     = (const float*)d_in[6];
    const float* W1     = (const float*)d_in[7];
    const float* b1     = (const float*)d_in[8];
    const float* ttt_g  = (const float*)d_in[9];
    const float* ttt_b  = (const float*)d_in[10];
    const float* lr_w   = (const float*)d_in[11];
    const float* lr_b   = (const float*)d_in[12];
    const float* post_g = (const float*)d_in[13];
    const float* post_b = (const float*)d_in[14];
    const float* norm_g = (const float*)d_in[15];
    const float* norm_b = (const float*)d_in[16];
    const float* W_up   = (const float*)d_in[17];
    const float* b_up   = (const float*)d_in[18];
    float* out = (float*)d_out;

    float* ws = (float*)d_ws;
    const size_t SZ = (size_t)MROWS * ADIM;      // 786432
    float* h    = ws;                // [4096][192]
    float* qb   = ws + SZ;           // [12][1024][64]
    float* kb   = ws + 2 * SZ;
    float* vb   = ws + 3 * SZ;       // after ab_kernel: a-vectors
    float* Gb   = ws + 4 * SZ;
    float2* er6b = (float2*)(ws + 5 * SZ);           // 12288 float2 (eta, r6)
    float* Ab   = ws + 5 * SZ + 24576;               // 393216
    float* Bb   = Ab + 393216;                       // 393216
    float* W0s  = Bb + 393216;                       // 1572864
    float* b0s  = W0s + 1572864;                     // 24576
    float2* lnst = (float2*)(b0s + 24576);           // 4096 float2
    // aliases (lifetime-disjoint)
    float* ysb  = h;    // post_kernel output (h dead after eta)
    float* tbuf = qb;   // ln(ys)@Wo (qb dead after post_kernel)

    // 1) h = silu(x @ W_down + b_down)
    gemm_k<1, 0, 0><<<dim3(ADIM / 64, MROWS / 64), 256, 0, stream>>>(
        x, W_down, b_down, h, MROWS, ADIM, DDIM, nullptr, nullptr, nullptr);
    // 2) q,k,v in ONE launch
    gemm_qkv<<<dim3(ADIM / 64, MROWS / 64, 3), 256, 0, stream>>>(
        h, Wq, Wk, Wv, qb);
    // 3) eta (per-row coalesced) -> er6b.x
    eta_kernel<<<MROWS, 192, 0, stream>>>(h, lr_w, lr_b, er6b);
    // 4) chunk coefficient matrices + a-vectors (in vb) + r6 -> er6b.y
    ab_kernel<<<BDIM * HDIM * NCHUNK, 256, 0, stream>>>(
        qb, kb, vb, ttt_g, ttt_b, Ab, Bb, er6b);
    // 5) sequential scan (merged 32-token pass, transient A-row loads)
    ttt_scan<<<BDIM * HDIM, 256, 0, stream>>>(
        kb, vb, er6b, Ab, W1, b1, ttt_g, ttt_b, Gb, W0s, b0s);
    // 6) outputs ys = q + ln(Zq)
    post_kernel<<<BDIM * HDIM * NCHUNK, 256, 0, stream>>>(
        qb, Bb, Gb, W0s, b0s, ttt_g, ttt_b, ysb);
    // 7) t = ln(ys) @ Wo   (LN fused into GEMM A-load)
    lnstats<<<MROWS, 64, 0, stream>>>(ysb, lnst);
    gemm_k<0, 0, 1><<<dim3(ADIM / 64, MROWS / 64), 256, 0, stream>>>(
        ysb, Wo, nullptr, tbuf, MROWS, ADIM, ADIM, lnst, post_g, post_b);
    // 8) out = ln(t) @ W_up + b_up   (LN fused into GEMM A-load)
    lnstats<<<MROWS, 64, 0, stream>>>(tbuf, lnst);
    gemm_k<0, 0, 1><<<dim3(DDIM / 64, MROWS / 64), 256, 0, stream>>>(
        tbuf, W_up, b_up, out, MROWS, DDIM, ADIM, lnst, norm_g, norm_b);
}

// Round 6
// 462.572 us; speedup vs baseline: 1.2421x; 1.2421x over previous
//
#include <hip/hip_runtime.h>
#include <hip/hip_bf16.h>
#include <math.h>

// Problem shape (fixed): B=4, S=1024, D=768, A=192, H=3, hd=64
#define BDIM 4
#define SDIM 1024
#define DDIM 768
#define ADIM 192
#define HDIM 3
#define HD   64
#define MROWS (BDIM*SDIM)      // 4096
#define NCHUNK (SDIM/32)       // 32
#define EPSLN 1e-6f

// ---------------- DPP wave reduction (64-lane sum, result broadcast) -------
template<int CTRL, int RMASK, bool BC>
__device__ __forceinline__ float dpp_add_step(float x) {
    int t = __builtin_amdgcn_update_dpp(0, __float_as_int(x), CTRL, RMASK, 0xf, BC);
    return x + __int_as_float(t);
}
__device__ __forceinline__ float wave_bcast_sum(float x) {
    x = dpp_add_step<0x111, 0xf, true >(x);
    x = dpp_add_step<0x112, 0xf, true >(x);
    x = dpp_add_step<0x114, 0xf, true >(x);
    x = dpp_add_step<0x118, 0xf, true >(x);
    x = dpp_add_step<0x142, 0xa, false>(x);
    x = dpp_add_step<0x143, 0xc, false>(x);
    return __int_as_float(__builtin_amdgcn_readlane(__float_as_int(x), 63));
}
__device__ __forceinline__ float rl(float v, int lane) {
    return __int_as_float(__builtin_amdgcn_readlane(__float_as_int(v), lane));
}
__device__ __forceinline__ float fast_rsq(float x) {
    float r;
    asm("v_rsq_f32 %0, %1" : "=v"(r) : "v"(x));
    return r;
}
// 5 simultaneous 64-lane sums via fused DPP adds (validated r7-r10).
__device__ __forceinline__ void red5_asm(float& a, float& b, float& c,
                                         float& d, float& e) {
#define R5_SHR(N)                                                              \
    asm("v_add_f32 %0, %0, %0 row_shr:" #N " row_mask:0xf bank_mask:0xf bound_ctrl:0" : "+v"(a)); \
    asm("v_add_f32 %0, %0, %0 row_shr:" #N " row_mask:0xf bank_mask:0xf bound_ctrl:0" : "+v"(b)); \
    asm("v_add_f32 %0, %0, %0 row_shr:" #N " row_mask:0xf bank_mask:0xf bound_ctrl:0" : "+v"(c)); \
    asm("v_add_f32 %0, %0, %0 row_shr:" #N " row_mask:0xf bank_mask:0xf bound_ctrl:0" : "+v"(d)); \
    asm("v_add_f32 %0, %0, %0 row_shr:" #N " row_mask:0xf bank_mask:0xf bound_ctrl:0" : "+v"(e));
#define R5_BC(N, RM)                                                           \
    asm("v_add_f32 %0, %0, %0 row_bcast:" #N " row_mask:" #RM " bank_mask:0xf" : "+v"(a)); \
    asm("v_add_f32 %0, %0, %0 row_bcast:" #N " row_mask:" #RM " bank_mask:0xf" : "+v"(b)); \
    asm("v_add_f32 %0, %0, %0 row_bcast:" #N " row_mask:" #RM " bank_mask:0xf" : "+v"(c)); \
    asm("v_add_f32 %0, %0, %0 row_bcast:" #N " row_mask:" #RM " bank_mask:0xf" : "+v"(d)); \
    asm("v_add_f32 %0, %0, %0 row_bcast:" #N " row_mask:" #RM " bank_mask:0xf" : "+v"(e));
    R5_SHR(1) R5_SHR(2) R5_SHR(4) R5_SHR(8)
    R5_BC(15, 0xa) R5_BC(31, 0xc)
#undef R5_SHR
#undef R5_BC
}

// ---------------- per-row LayerNorm stats: (mu, rstd) over 192 -------------
__global__ __launch_bounds__(64) void lnstats(
    const float* __restrict__ in, float2* __restrict__ st)
{
    int row = blockIdx.x, tid = threadIdx.x;
    float x0 = in[(size_t)row * ADIM + tid];
    float x1 = in[(size_t)row * ADIM + 64 + tid];
    float x2 = in[(size_t)row * ADIM + 128 + tid];
    float s1 = wave_bcast_sum((x0 + x1) + x2);
    float s2 = wave_bcast_sum(fmaf(x0, x0, fmaf(x1, x1, x2 * x2)));
    if (tid == 0) {
        float mu = s1 * (1.f / 192.f);
        float var = s2 * (1.f / 192.f) - mu * mu;
        st[row] = make_float2(mu, rsqrtf(var + EPSLN));
    }
}

// ---------------- Generic fp32 tiled GEMM: C = act(lnA(A)@B + bias) --------
template<int ACT, int LAYOUT, int LNA>
__global__ __launch_bounds__(256) void gemm_k(
    const float* __restrict__ A, const float* __restrict__ Bm,
    const float* __restrict__ bias, float* __restrict__ C,
    int M, int N, int K,
    const float2* __restrict__ lnst, const float* __restrict__ lng,
    const float* __restrict__ lnbb)
{
    __shared__ float As[16][68];
    __shared__ float Bs[16][68];
    const int tid = threadIdx.x;
    const int bm = blockIdx.y * 64, bn = blockIdx.x * 64;
    const int tr = tid >> 4, tc = tid & 15;
    float acc[4][4] = {};

    for (int k0 = 0; k0 < K; k0 += 16) {
        #pragma unroll
        for (int p = 0; p < 4; ++p) {
            int m = (tid >> 4) + p * 16;
            int kk = tid & 15;
            float av = A[(size_t)(bm + m) * K + k0 + kk];
            if (LNA) {
                float2 stv = lnst[bm + m];
                av = fmaf((av - stv.x) * stv.y, lng[k0 + kk], lnbb[k0 + kk]);
            }
            As[kk][m] = av;
        }
        #pragma unroll
        for (int p = 0; p < 4; ++p) {
            int kk = (tid >> 6) + p * 4;
            int n = tid & 63;
            Bs[kk][n] = Bm[(size_t)(k0 + kk) * N + bn + n];
        }
        __syncthreads();
        #pragma unroll
        for (int kk = 0; kk < 16; ++kk) {
            // 16B-aligned: As row stride 272B, offsets are multiples of 16B
            const float4 a4 = *(const float4*)&As[kk][tr * 4];
            const float4 b4 = *(const float4*)&Bs[kk][tc * 4];
            float aa[4] = {a4.x, a4.y, a4.z, a4.w};
            float bb[4] = {b4.x, b4.y, b4.z, b4.w};
            #pragma unroll
            for (int i = 0; i < 4; ++i)
                #pragma unroll
                for (int j = 0; j < 4; ++j)
                    acc[i][j] = fmaf(aa[i], bb[j], acc[i][j]);
        }
        __syncthreads();
    }

    #pragma unroll
    for (int i = 0; i < 4; ++i) {
        int m = bm + tr * 4 + i;
        #pragma unroll
        for (int j = 0; j < 4; ++j) {
            int n = bn + tc * 4 + j;
            float v = acc[i][j];
            if (bias) v += bias[n];
            if (ACT == 1) v = v / (1.f + __expf(-v));   // silu
            if (LAYOUT == 0) {
                C[(size_t)m * N + n] = v;
            } else {
                int b  = m >> 10, s = m & 1023;
                int hh = n >> 6,  d = n & 63;
                C[(((size_t)b * HDIM + hh) * SDIM + s) * HD + d] = v;
            }
        }
    }
}

// ---------------- fused QKV GEMM: one launch, blockIdx.z picks the head ----
__global__ __launch_bounds__(256) void gemm_qkv(
    const float* __restrict__ A, const float* __restrict__ BWq,
    const float* __restrict__ BWk, const float* __restrict__ BWv,
    float* __restrict__ Cbase)
{
    const float* Bm = (blockIdx.z == 0) ? BWq : (blockIdx.z == 1) ? BWk : BWv;
    float* C = Cbase + (size_t)blockIdx.z * ((size_t)MROWS * ADIM);
    __shared__ float As[16][68];
    __shared__ float Bs[16][68];
    const int tid = threadIdx.x;
    const int bm = blockIdx.y * 64, bn = blockIdx.x * 64;
    const int tr = tid >> 4, tc = tid & 15;
    float acc[4][4] = {};

    for (int k0 = 0; k0 < ADIM; k0 += 16) {
        #pragma unroll
        for (int p = 0; p < 4; ++p) {
            int m = (tid >> 4) + p * 16;
            int kk = tid & 15;
            As[kk][m] = A[(size_t)(bm + m) * ADIM + k0 + kk];
        }
        #pragma unroll
        for (int p = 0; p < 4; ++p) {
            int kk = (tid >> 6) + p * 4;
            int n = tid & 63;
            Bs[kk][n] = Bm[(size_t)(k0 + kk) * ADIM + bn + n];
        }
        __syncthreads();
        #pragma unroll
        for (int kk = 0; kk < 16; ++kk) {
            const float4 a4 = *(const float4*)&As[kk][tr * 4];
            const float4 b4 = *(const float4*)&Bs[kk][tc * 4];
            float aa[4] = {a4.x, a4.y, a4.z, a4.w};
            float bb[4] = {b4.x, b4.y, b4.z, b4.w};
            #pragma unroll
            for (int i = 0; i < 4; ++i)
                #pragma unroll
                for (int j = 0; j < 4; ++j)
                    acc[i][j] = fmaf(aa[i], bb[j], acc[i][j]);
        }
        __syncthreads();
    }

    #pragma unroll
    for (int i = 0; i < 4; ++i) {
        int m = bm + tr * 4 + i;
        #pragma unroll
        for (int j = 0; j < 4; ++j) {
            int n = bn + tc * 4 + j;
            int b  = m >> 10, s = m & 1023;
            int hh = n >> 6,  d = n & 63;
            C[(((size_t)b * HDIM + hh) * SDIM + s) * HD + d] = acc[i][j];
        }
    }
}

// ---------------- eta = sigmoid(h @ lr_w + lr_b) / hd  (per-row block) -----
__global__ __launch_bounds__(192) void eta_kernel(
    const float* __restrict__ h, const float* __restrict__ lr_w,
    const float* __restrict__ lr_b, float* __restrict__ etab)
{
    const int row = blockIdx.x, tid = threadIdx.x, wave = tid >> 6;
    __shared__ float part[3][3];   // [wave][hh]
    float hv = h[(size_t)row * ADIM + tid];
    float p0 = hv * lr_w[tid * 3 + 0];
    float p1 = hv * lr_w[tid * 3 + 1];
    float p2 = hv * lr_w[tid * 3 + 2];
    float s0 = wave_bcast_sum(p0);
    float s1 = wave_bcast_sum(p1);
    float s2 = wave_bcast_sum(p2);
    if ((tid & 63) == 0) {
        part[wave][0] = s0; part[wave][1] = s1; part[wave][2] = s2;
    }
    __syncthreads();
    if (tid < 3) {
        float acc = (part[0][tid] + part[1][tid]) + part[2][tid] + lr_b[tid];
        float e = 1.f / (1.f + __expf(-acc)) * (1.f / 64.f);
        int b = row >> 10, s = row & 1023;
        etab[((size_t)(b * HDIM + tid)) * SDIM + s] = e;
    }
}

// -- pre: A=[k.k+1], B=[q.k+1], a-vectors (into vb), r6 ----------------------
__global__ __launch_bounds__(256) void ab_kernel(
    const float* __restrict__ qb, const float* __restrict__ kb,
    float* __restrict__ vb,            // in: v; out: a = (bw-(v-k))*gw
    const float* __restrict__ ttt_g, const float* __restrict__ ttt_b,
    float* __restrict__ Ab, float* __restrict__ Bb,
    float* __restrict__ r6b)
{
    int bh = blockIdx.x >> 5, c = blockIdx.x & 31, cs = c * 32;
    int hh = bh % HDIM;
    __shared__ float Kc[32][65], Qc[32][65], Vc[32][65];
    for (int i = threadIdx.x; i < 2048; i += 256) {
        int t = i >> 6, j = i & 63;
        Kc[t][j] = kb[((size_t)bh * SDIM + cs + t) * HD + j];
        Qc[t][j] = qb[((size_t)bh * SDIM + cs + t) * HD + j];
        Vc[t][j] = vb[((size_t)bh * SDIM + cs + t) * HD + j];
    }
    __syncthreads();
    size_t base = ((size_t)(bh * NCHUNK + c)) * 1024;
    for (int e = threadIdx.x; e < 1024; e += 256) {
        int t = e >> 5, s = e & 31;
        float a = 1.f, b = 1.f;
        #pragma unroll
        for (int j = 0; j < 64; ++j) {
            float ks = Kc[s][j];
            a = fmaf(Kc[t][j], ks, a);
            b = fmaf(Qc[t][j], ks, b);
        }
        Ab[base + e] = a;
        Bb[base + e] = b;
    }
    for (int i = threadIdx.x; i < 2048; i += 256) {
        int t = i >> 6, j = i & 63;
        float gwv = ttt_g[hh * 64 + j], bwv = ttt_b[hh * 64 + j];
        float av = fmaf(-(Vc[t][j] - Kc[t][j]), gwv, bwv * gwv);
        Vc[t][j] = av;
        vb[((size_t)bh * SDIM + cs + t) * HD + j] = av;
    }
    __syncthreads();
    if (threadIdx.x < 32) {
        int t = threadIdx.x;
        float acc = 0.f;
        #pragma unroll
        for (int j = 0; j < 64; ++j) acc += Vc[t][j];
        r6b[(size_t)bh * SDIM + cs + t] = acc;
    }
}

// ---------------- staging helper (global -> LDS, float4) -------------------
__device__ __forceinline__ void stage_chunk(
    int pp, int cc, int bh, int idx, int nth,
    const float* __restrict__ kbuf, const float* __restrict__ abuf,
    const float* __restrict__ Ab, const float* __restrict__ etab,
    const float* __restrict__ r6b,
    float4* K4, float4* a4, float4* A4, float2* er6)
{
    const float4* kg = (const float4*)(kbuf + ((size_t)bh * SDIM + cc * 32) * HD);
    const float4* ag = (const float4*)(abuf + ((size_t)bh * SDIM + cc * 32) * HD);
    const float4* Ag = (const float4*)(Ab + ((size_t)(bh * NCHUNK + cc)) * 1024);
    for (int i = idx; i < 512; i += nth) K4[pp * 512 + i] = kg[i];
    for (int i = idx; i < 512; i += nth) a4[pp * 512 + i] = ag[i];
    for (int i = idx; i < 256; i += nth) A4[pp * 256 + i] = Ag[i];
    for (int i = idx; i < 32; i += nth)
        er6[pp * 32 + i] = make_float2(
            etab[(size_t)bh * SDIM + cc * 32 + i] * (1.f / 64.f),
            r6b[(size_t)bh * SDIM + cc * 32 + i]);
}

// ---------------- the sequential TTT scan (12 blocks) — r10 + 3 micro-wins -
// r16: REVERT to the proven r10 two-half structure (merged-32 arc r12-r15
// regressed: Z[32]+state > register file -> AGPR/spill VALU ops inside the
// serial chain; counter evidence: +75% VALU-busy cycles at +4% source instrs.
// The mid-chunk W round-trip IS the deferred A@G half-1 update at equal FLOP
// cost — not removable overhead). Micro-wins vs r10, each audited:
//  1. s_setprio(1/0) around wave 0's serial section.
//  2. breg folded into wave 1's P1 partial (identical breg on all waves).
//  3. avN prefetch trimmed to needed quads: q >= ((I)+2)>>2 (compile-time).
__global__ __launch_bounds__(256, 1) void ttt_scan(
    const float* __restrict__ kbuf, const float* __restrict__ abuf,
    const float* __restrict__ etab, const float* __restrict__ Ab,
    const float* __restrict__ r6b,
    const float* __restrict__ W1,   const float* __restrict__ b1,
    const float* __restrict__ ttt_g, const float* __restrict__ ttt_b,
    float* __restrict__ Gbuf, float* __restrict__ W0save, float* __restrict__ b0save)
{
    const int bh = blockIdx.x, hh = bh % HDIM;
    const int tid = threadIdx.x, lane = tid & 63;
    const int wv = tid >> 6;
    __shared__ float  Zp[4][16][64];   // 16 KB (slice 0 unused)
    __shared__ float4 K4s[2 * 512];    // 16 KB: K double-buffered
    __shared__ float4 a4s[2 * 512];    // 16 KB: a double-buffered
    __shared__ float4 A4s[2 * 256];    //  8 KB: A double-buffered
    __shared__ float2 er6s[2 * 32];    // 512 B
    __shared__ float  Gl[16][64];      //  4 KB: per-token eta*g (sub-chunk)

    float Wreg[16];
    #pragma unroll
    for (int r = 0; r < 16; ++r)
        Wreg[r] = W1[hh * 4096 + (wv * 16 + r) * 64 + lane];
    float breg = b1[hh * 64 + lane];
    const float gw = ttt_g[hh * 64 + lane];
    const float bw = ttt_b[hh * 64 + lane];
    const float w3 = gw * gw;
    (void)bw;
    const float Cg2 = wave_bcast_sum(w3);
    const float* a_f = (const float*)a4s;

    stage_chunk(0, 0, bh, tid, 256, kbuf, abuf, Ab, etab, r6b,
                K4s, a4s, A4s, er6s);
    __syncthreads();

    for (int c = 0; c < NCHUNK; ++c) {
        const int cs = c * 32;
        const int p = c & 1;

        {
            float* Wd = W0save + ((size_t)(bh * NCHUNK + c)) * 4096
                        + (wv * 16) * 64 + lane;
            #pragma unroll
            for (int r = 0; r < 16; ++r) Wd[r * 64] = Wreg[r];
            if (tid < 64) b0save[(bh * NCHUNK + c) * 64 + tid] = breg;
        }

        #pragma unroll
        for (int h = 0; h < 2; ++h) {
            const int h16 = h * 16, h4 = h * 4;

            // ---- P1 (all waves): Z0 partials for tokens [h16, h16+16) ----
            float Zt[16];
            #pragma unroll
            for (int i = 0; i < 16; ++i) {
                const int t = h16 + i;
                float zt = 0.f;
                #pragma unroll
                for (int r4 = 0; r4 < 4; ++r4) {
                    const float4 kv = K4s[p * 512 + t * 16 + wv * 4 + r4];
                    zt = fmaf(kv.x, Wreg[r4 * 4 + 0], zt);
                    zt = fmaf(kv.y, Wreg[r4 * 4 + 1], zt);
                    zt = fmaf(kv.z, Wreg[r4 * 4 + 2], zt);
                    zt = fmaf(kv.w, Wreg[r4 * 4 + 3], zt);
                }
                Zt[i] = zt;
            }
            if (wv != 0) {
                #pragma unroll
                for (int i = 0; i < 16; ++i)
                    Zp[wv][i][lane] = (wv == 1) ? Zt[i] + breg : Zt[i];
            }
            __syncthreads();   // (A) Zp ready; buffer p staged

            // ---- P2: wave 0 serial; waves 1-3 stage next chunk (h==0) ----
            if (wv == 0) {
                __builtin_amdgcn_s_setprio(1);
                float Z[16];
                #pragma unroll
                for (int i = 0; i < 16; ++i) {
                    float q1 = Zp[1][i][lane], q2 = Zp[2][i][lane],
                          q3 = Zp[3][i][lane];
                    Z[i] = ((Zt[i] + q1) + (q2 + q3));
                }
                float4 avA[4], avB[4];
                float aA, aB; float2 erA, erB;
                #pragma unroll
                for (int q = 0; q < 4; ++q)
                    avA[q] = A4s[p * 256 + h16 * 8 + h4 + q];
                aA  = a_f[p * 2048 + h16 * 64 + lane];
                erA = er6s[p * 32 + h16];
#define TOK(I, avC, aC, erC, avN, aN, erN)                                     \
    {                                                                          \
        if ((I) < 15) {                                                        \
            _Pragma("unroll")                                                  \
            for (int q = ((I) + 2) >> 2; q < 4; ++q)                           \
                avN[q] = A4s[p * 256 + (h16 + (I) + 1) * 8 + h4 + q];          \
            aN  = a_f[p * 2048 + (h16 + (I) + 1) * 64 + lane];                 \
            erN = er6s[p * 32 + h16 + (I) + 1];                                \
        }                                                                      \
        float z  = Z[I];                                                       \
        float a  = aC;                                                         \
        float zg = z * w3;                                                     \
        float x1 = z, x2 = z * z, x3 = zg, x4 = zg * z, x5 = z * a;            \
        red5_asm(x1, x2, x3, x4, x5);                                          \
        float r1 = rl(x1, 63), r2 = rl(x2, 63), r3 = rl(x3, 63);               \
        float r4 = rl(x4, 63), r5 = rl(x5, 63);                                \
        float r6t = (erC).y;                                                   \
        float mu   = r1 * (1.f / 64.f);                                        \
        float var  = fmaf(-mu, mu, r2 * (1.f / 64.f));                         \
        float rstd = fast_rsq(var + EPSLN);                                    \
        float mc   = mu * Cg2;                                                 \
        float sgxh = fmaf(rstd, r3 - mc, r6t);                                 \
        float t4v  = fmaf(mu, mc, fmaf(-2.f * mu, r3, r4));                    \
        float sgz  = fmaf(rstd * rstd, t4v, rstd * (r5 - mu * r6t));           \
        float zh   = (z - mu) * rstd;                                          \
        float gxh  = fmaf(zh, w3, a);                                          \
        float ge   = (fmaf(64.f, gxh, -sgxh) - zh * sgz) * (rstd * (erC).x);   \
        Gl[I][lane] = ge;                                                      \
        _Pragma("unroll")                                                      \
        for (int u = (I) + 1; u < 16; ++u) {                                   \
            const float4 c4 = avC[(u) >> 2]; const int m4 = (u) & 3;           \
            float Atu = (m4 == 0) ? c4.x : (m4 == 1) ? c4.y                    \
                      : (m4 == 2) ? c4.z : c4.w;                               \
            Z[u] = fmaf(-Atu, ge, Z[u]);                                       \
        }                                                                      \
    }
                #pragma unroll
                for (int tp = 0; tp < 8; ++tp) {
                    TOK(2 * tp,     avA, aA, erA, avB, aB, erB)
                    TOK(2 * tp + 1, avB, aB, erB, avA, aA, erA)
                }
#undef TOK
                __builtin_amdgcn_s_setprio(0);
            } else if (h == 0 && c < NCHUNK - 1) {
                stage_chunk(p ^ 1, c + 1, bh, tid - 64, 192,
                            kbuf, abuf, Ab, etab, r6b, K4s, a4s, A4s, er6s);
            }
            __syncthreads();   // (B) Gl ready; staging (h==0) done

            // ---- P3 (all waves): W -= K^T@G ; b -= colsum(G); Gbuf -------
            float btot = 0.f;
            #pragma unroll
            for (int s = 0; s < 16; ++s) {
                float gd = Gl[s][lane];
                btot += gd;
                #pragma unroll
                for (int r4 = 0; r4 < 4; ++r4) {
                    const float4 kv = K4s[p * 512 + (h16 + s) * 16 + wv * 4 + r4];
                    Wreg[r4 * 4 + 0] = fmaf(-kv.x, gd, Wreg[r4 * 4 + 0]);
                    Wreg[r4 * 4 + 1] = fmaf(-kv.y, gd, Wreg[r4 * 4 + 1]);
                    Wreg[r4 * 4 + 2] = fmaf(-kv.z, gd, Wreg[r4 * 4 + 2]);
                    Wreg[r4 * 4 + 3] = fmaf(-kv.w, gd, Wreg[r4 * 4 + 3]);
                }
            }
            breg -= btot;
            {
                float* gb = Gbuf + ((size_t)bh * SDIM + cs + h16) * HD + lane;
                #pragma unroll
                for (int r = 0; r < 4; ++r)
                    gb[(wv * 4 + r) * HD] = Gl[wv * 4 + r][lane];
            }
        }
    }
}

// ---------------- post: Zq = Qc@W0 + b0 - tril(B)@G ; ys = q + ln(Zq) ------
__global__ __launch_bounds__(256) void post_kernel(
    const float* __restrict__ qbuf, const float* __restrict__ Bb,
    const float* __restrict__ Gbuf, const float* __restrict__ W0save,
    const float* __restrict__ b0save,
    const float* __restrict__ ttt_g, const float* __restrict__ ttt_b,
    float* __restrict__ ys)
{
    const int bh = blockIdx.x >> 5, c = blockIdx.x & 31, cs = c * 32;
    const int b = bh / HDIM, hh = bh % HDIM;
    const int tid = threadIdx.x, lane = tid & 63, wave = tid >> 6;
    __shared__ float Qc[32][65];
    __shared__ float W0l[64][65];
    __shared__ float Gl[32][64];
    for (int i = tid; i < 2048; i += 256) {
        int t = i >> 6, j = i & 63;
        Qc[t][j] = qbuf[((size_t)bh * SDIM + cs + t) * HD + j];
        Gl[t][j] = Gbuf[((size_t)bh * SDIM + cs + t) * HD + j];
    }
    for (int i = tid; i < 4096; i += 256)
        W0l[i >> 6][i & 63] = W0save[((size_t)(bh * NCHUNK + c)) * 4096 + i];
    __syncthreads();

    const float bb0 = b0save[(bh * NCHUNK + c) * 64 + lane];
    const float gw = ttt_g[hh * 64 + lane], bw = ttt_b[hh * 64 + lane];
    float acc[8];
    #pragma unroll
    for (int r = 0; r < 8; ++r) acc[r] = bb0;
    for (int j = 0; j < 64; ++j) {
        float w0 = W0l[j][lane];
        #pragma unroll
        for (int r = 0; r < 8; ++r)
            acc[r] = fmaf(Qc[wave * 8 + r][j], w0, acc[r]);
    }
    float Breg[8];
    size_t bbase = ((size_t)(bh * NCHUNK + c)) * 1024;
    #pragma unroll
    for (int r = 0; r < 8; ++r)
        Breg[r] = Bb[bbase + (wave * 8 + r) * 32 + (lane & 31)];
    #pragma unroll
    for (int s = 0; s < 32; ++s) {
        float gd = Gl[s][lane];
        #pragma unroll
        for (int r = 0; r < 8; ++r) {
            int t = wave * 8 + r;
            float Bts = rl(Breg[r], s);
            acc[r] = (s <= t) ? fmaf(-Bts, gd, acc[r]) : acc[r];
        }
    }
    #pragma unroll
    for (int r = 0; r < 8; ++r) {
        int t = wave * 8 + r;
        float s1 = wave_bcast_sum(acc[r]);
        float s2 = wave_bcast_sum(acc[r] * acc[r]);
        float mu = s1 * (1.f / 64.f);
        float var = s2 * (1.f / 64.f) - mu * mu;
        float rstd = rsqrtf(var + EPSLN);
        float zh = (acc[r] - mu) * rstd;
        float val = zh * gw + bw + Qc[t][lane];
        ys[((size_t)(b * SDIM) + cs + t) * ADIM + hh * HD + lane] = val;
    }
}

// ---------------- launch ---------------------------------------------------
extern "C" void kernel_launch(void* const* d_in, const int* in_sizes, int n_in,
                              void* d_out, int out_size, void* d_ws, size_t ws_size,
                              hipStream_t stream)
{
    const float* x      = (const float*)d_in[0];
    const float* W_down = (const float*)d_in[1];
    const float* b_down = (const float*)d_in[2];
    const float* Wq     = (const float*)d_in[3];
    const float* Wk     = (const float*)d_in[4];
    const float* Wv     = (const float*)d_in[5];
    const float* Wo     = (const float*)d_in[6];
    const float* W1     = (const float*)d_in[7];
    const float* b1     = (const float*)d_in[8];
    const float* ttt_g  = (const float*)d_in[9];
    const float* ttt_b  = (const float*)d_in[10];
    const float* lr_w   = (const float*)d_in[11];
    const float* lr_b   = (const float*)d_in[12];
    const float* post_g = (const float*)d_in[13];
    const float* post_b = (const float*)d_in[14];
    const float* norm_g = (const float*)d_in[15];
    const float* norm_b = (const float*)d_in[16];
    const float* W_up   = (const float*)d_in[17];
    const float* b_up   = (const float*)d_in[18];
    float* out = (float*)d_out;

    float* ws = (float*)d_ws;
    const size_t SZ = (size_t)MROWS * ADIM;      // 786432
    float* h    = ws;                // [4096][192]
    float* qb   = ws + SZ;           // [12][1024][64]
    float* kb   = ws + 2 * SZ;
    float* vb   = ws + 3 * SZ;       // after ab_kernel: a-vectors
    float* Gb   = ws + 4 * SZ;
    float* etab = ws + 5 * SZ;                       // 12288
    float* Ab   = etab + 12288;                      // 393216
    float* Bb   = Ab + 393216;                       // 393216
    float* W0s  = Bb + 393216;                       // 1572864
    float* b0s  = W0s + 1572864;                     // 24576
    float* r6b  = b0s + 24576;                       // 12288
    float2* lnst = (float2*)(r6b + 12288);           // 4096 float2
    // aliases (lifetime-disjoint)
    float* ysb  = h;    // post_kernel output (h dead after eta)
    float* tbuf = qb;   // ln(ys)@Wo (qb dead after post_kernel)

    // 1) h = silu(x @ W_down + b_down)
    gemm_k<1, 0, 0><<<dim3(ADIM / 64, MROWS / 64), 256, 0, stream>>>(
        x, W_down, b_down, h, MROWS, ADIM, DDIM, nullptr, nullptr, nullptr);
    // 2) q,k,v in ONE launch
    gemm_qkv<<<dim3(ADIM / 64, MROWS / 64, 3), 256, 0, stream>>>(
        h, Wq, Wk, Wv, qb);
    // 3) eta (per-row coalesced)
    eta_kernel<<<MROWS, 192, 0, stream>>>(h, lr_w, lr_b, etab);
    // 4) chunk coefficient matrices + a-vectors (in vb) + r6
    ab_kernel<<<BDIM * HDIM * NCHUNK, 256, 0, stream>>>(
        qb, kb, vb, ttt_g, ttt_b, Ab, Bb, r6b);
    // 5) sequential scan (r10 structure + setprio/breg-fold/prefetch-trim)
    ttt_scan<<<BDIM * HDIM, 256, 0, stream>>>(
        kb, vb, etab, Ab, r6b, W1, b1, ttt_g, ttt_b, Gb, W0s, b0s);
    // 6) outputs ys = q + ln(Zq)
    post_kernel<<<BDIM * HDIM * NCHUNK, 256, 0, stream>>>(
        qb, Bb, Gb, W0s, b0s, ttt_g, ttt_b, ysb);
    // 7) t = ln(ys) @ Wo   (LN fused into GEMM A-load)
    lnstats<<<MROWS, 64, 0, stream>>>(ysb, lnst);
    gemm_k<0, 0, 1><<<dim3(ADIM / 64, MROWS / 64), 256, 0, stream>>>(
        ysb, Wo, nullptr, tbuf, MROWS, ADIM, ADIM, lnst, post_g, post_b);
    // 8) out = ln(t) @ W_up + b_up   (LN fused into GEMM A-load)
    lnstats<<<MROWS, 64, 0, stream>>>(tbuf, lnst);
    gemm_k<0, 0, 1><<<dim3(DDIM / 64, MROWS / 64), 256, 0, stream>>>(
        tbuf, W_up, b_up, out, MROWS, DDIM, ADIM, lnst, norm_g, norm_b);
}

// Round 7
// 455.280 us; speedup vs baseline: 1.2620x; 1.0160x over previous
//
#include <hip/hip_runtime.h>
#include <hip/hip_bf16.h>
#include <math.h>

// Problem shape (fixed): B=4, S=1024, D=768, A=192, H=3, hd=64
#define BDIM 4
#define SDIM 1024
#define DDIM 768
#define ADIM 192
#define HDIM 3
#define HD   64
#define MROWS (BDIM*SDIM)      // 4096
#define NCHUNK (SDIM/32)       // 32
#define EPSLN 1e-6f

// ---------------- DPP wave reduction (64-lane sum, result broadcast) -------
template<int CTRL, int RMASK, bool BC>
__device__ __forceinline__ float dpp_add_step(float x) {
    int t = __builtin_amdgcn_update_dpp(0, __float_as_int(x), CTRL, RMASK, 0xf, BC);
    return x + __int_as_float(t);
}
__device__ __forceinline__ float wave_bcast_sum(float x) {
    x = dpp_add_step<0x111, 0xf, true >(x);
    x = dpp_add_step<0x112, 0xf, true >(x);
    x = dpp_add_step<0x114, 0xf, true >(x);
    x = dpp_add_step<0x118, 0xf, true >(x);
    x = dpp_add_step<0x142, 0xa, false>(x);
    x = dpp_add_step<0x143, 0xc, false>(x);
    return __int_as_float(__builtin_amdgcn_readlane(__float_as_int(x), 63));
}
// 16-lane (DPP-row) prefix sum; lane 15 of each row holds the row total.
__device__ __forceinline__ float dpp_row16_sum(float x) {
    x = dpp_add_step<0x111, 0xf, true >(x);
    x = dpp_add_step<0x112, 0xf, true >(x);
    x = dpp_add_step<0x114, 0xf, true >(x);
    x = dpp_add_step<0x118, 0xf, true >(x);
    return x;
}
__device__ __forceinline__ float rl(float v, int lane) {
    return __int_as_float(__builtin_amdgcn_readlane(__float_as_int(v), lane));
}
__device__ __forceinline__ float fast_rsq(float x) {
    float r;
    asm("v_rsq_f32 %0, %1" : "=v"(r) : "v"(x));
    return r;
}
// 5 simultaneous 64-lane sums via fused DPP adds (validated r7-r10).
__device__ __forceinline__ void red5_asm(float& a, float& b, float& c,
                                         float& d, float& e) {
#define R5_SHR(N)                                                              \
    asm("v_add_f32 %0, %0, %0 row_shr:" #N " row_mask:0xf bank_mask:0xf bound_ctrl:0" : "+v"(a)); \
    asm("v_add_f32 %0, %0, %0 row_shr:" #N " row_mask:0xf bank_mask:0xf bound_ctrl:0" : "+v"(b)); \
    asm("v_add_f32 %0, %0, %0 row_shr:" #N " row_mask:0xf bank_mask:0xf bound_ctrl:0" : "+v"(c)); \
    asm("v_add_f32 %0, %0, %0 row_shr:" #N " row_mask:0xf bank_mask:0xf bound_ctrl:0" : "+v"(d)); \
    asm("v_add_f32 %0, %0, %0 row_shr:" #N " row_mask:0xf bank_mask:0xf bound_ctrl:0" : "+v"(e));
#define R5_BC(N, RM)                                                           \
    asm("v_add_f32 %0, %0, %0 row_bcast:" #N " row_mask:" #RM " bank_mask:0xf" : "+v"(a)); \
    asm("v_add_f32 %0, %0, %0 row_bcast:" #N " row_mask:" #RM " bank_mask:0xf" : "+v"(b)); \
    asm("v_add_f32 %0, %0, %0 row_bcast:" #N " row_mask:" #RM " bank_mask:0xf" : "+v"(c)); \
    asm("v_add_f32 %0, %0, %0 row_bcast:" #N " row_mask:" #RM " bank_mask:0xf" : "+v"(d)); \
    asm("v_add_f32 %0, %0, %0 row_bcast:" #N " row_mask:" #RM " bank_mask:0xf" : "+v"(e));
    R5_SHR(1) R5_SHR(2) R5_SHR(4) R5_SHR(8)
    R5_BC(15, 0xa) R5_BC(31, 0xc)
#undef R5_SHR
#undef R5_BC
}

// ---------------- Generic fp32 tiled GEMM ----------------------------------
// LNA: 0 = plain A-load; 2 = LayerNorm A from raw (Sum, SumSq) row stats.
// STATS: 1 = accumulate per-row (Sum, SumSq) of OUTPUT into ostat (atomics).
template<int ACT, int LAYOUT, int LNA, int STATS>
__global__ __launch_bounds__(256) void gemm_k(
    const float* __restrict__ A, const float* __restrict__ Bm,
    const float* __restrict__ bias, float* __restrict__ C,
    int M, int N, int K,
    const float2* __restrict__ lnst, const float* __restrict__ lng,
    const float* __restrict__ lnbb, float2* __restrict__ ostat)
{
    __shared__ float As[16][68];
    __shared__ float Bs[16][68];
    __shared__ float2 lst[64];
    const int tid = threadIdx.x;
    const int bm = blockIdx.y * 64, bn = blockIdx.x * 64;
    const int tr = tid >> 4, tc = tid & 15;
    float acc[4][4] = {};

    if (LNA == 2) {
        if (tid < 64) {
            float2 s = lnst[bm + tid];
            float mu = s.x * (1.f / 192.f);
            float var = fmaf(-mu, mu, s.y * (1.f / 192.f));
            lst[tid] = make_float2(mu, rsqrtf(var + EPSLN));
        }
        __syncthreads();
    }

    for (int k0 = 0; k0 < K; k0 += 16) {
        #pragma unroll
        for (int p = 0; p < 4; ++p) {
            int m = (tid >> 4) + p * 16;
            int kk = tid & 15;
            float av = A[(size_t)(bm + m) * K + k0 + kk];
            if (LNA == 2) {
                float2 stv = lst[m];
                av = fmaf((av - stv.x) * stv.y, lng[k0 + kk], lnbb[k0 + kk]);
            }
            As[kk][m] = av;
        }
        #pragma unroll
        for (int p = 0; p < 4; ++p) {
            int kk = (tid >> 6) + p * 4;
            int n = tid & 63;
            Bs[kk][n] = Bm[(size_t)(k0 + kk) * N + bn + n];
        }
        __syncthreads();
        #pragma unroll
        for (int kk = 0; kk < 16; ++kk) {
            // 16B-aligned: As row stride 272B, offsets are multiples of 16B
            const float4 a4 = *(const float4*)&As[kk][tr * 4];
            const float4 b4 = *(const float4*)&Bs[kk][tc * 4];
            float aa[4] = {a4.x, a4.y, a4.z, a4.w};
            float bb[4] = {b4.x, b4.y, b4.z, b4.w};
            #pragma unroll
            for (int i = 0; i < 4; ++i)
                #pragma unroll
                for (int j = 0; j < 4; ++j)
                    acc[i][j] = fmaf(aa[i], bb[j], acc[i][j]);
        }
        __syncthreads();
    }

    float rs1[4] = {}, rs2[4] = {};
    #pragma unroll
    for (int i = 0; i < 4; ++i) {
        int m = bm + tr * 4 + i;
        #pragma unroll
        for (int j = 0; j < 4; ++j) {
            int n = bn + tc * 4 + j;
            float v = acc[i][j];
            if (bias) v += bias[n];
            if (ACT == 1) v = v / (1.f + __expf(-v));   // silu
            if (STATS) { rs1[i] += v; rs2[i] = fmaf(v, v, rs2[i]); }
            if (LAYOUT == 0) {
                C[(size_t)m * N + n] = v;
            } else {
                int b  = m >> 10, s = m & 1023;
                int hh = n >> 6,  d = n & 63;
                C[(((size_t)b * HDIM + hh) * SDIM + s) * HD + d] = v;
            }
        }
    }
    if (STATS) {
        #pragma unroll
        for (int i = 0; i < 4; ++i) {
            rs1[i] = dpp_row16_sum(rs1[i]);
            rs2[i] = dpp_row16_sum(rs2[i]);
        }
        if (tc == 15) {
            #pragma unroll
            for (int i = 0; i < 4; ++i) {
                atomicAdd(&ostat[bm + tr * 4 + i].x, rs1[i]);
                atomicAdd(&ostat[bm + tr * 4 + i].y, rs2[i]);
            }
        }
    }
}

// ---------------- fused QKV GEMM: one launch, blockIdx.z picks the head ----
__global__ __launch_bounds__(256) void gemm_qkv(
    const float* __restrict__ A, const float* __restrict__ BWq,
    const float* __restrict__ BWk, const float* __restrict__ BWv,
    float* __restrict__ Cbase)
{
    const float* Bm = (blockIdx.z == 0) ? BWq : (blockIdx.z == 1) ? BWk : BWv;
    float* C = Cbase + (size_t)blockIdx.z * ((size_t)MROWS * ADIM);
    __shared__ float As[16][68];
    __shared__ float Bs[16][68];
    const int tid = threadIdx.x;
    const int bm = blockIdx.y * 64, bn = blockIdx.x * 64;
    const int tr = tid >> 4, tc = tid & 15;
    float acc[4][4] = {};

    for (int k0 = 0; k0 < ADIM; k0 += 16) {
        #pragma unroll
        for (int p = 0; p < 4; ++p) {
            int m = (tid >> 4) + p * 16;
            int kk = tid & 15;
            As[kk][m] = A[(size_t)(bm + m) * ADIM + k0 + kk];
        }
        #pragma unroll
        for (int p = 0; p < 4; ++p) {
            int kk = (tid >> 6) + p * 4;
            int n = tid & 63;
            Bs[kk][n] = Bm[(size_t)(k0 + kk) * ADIM + bn + n];
        }
        __syncthreads();
        #pragma unroll
        for (int kk = 0; kk < 16; ++kk) {
            const float4 a4 = *(const float4*)&As[kk][tr * 4];
            const float4 b4 = *(const float4*)&Bs[kk][tc * 4];
            float aa[4] = {a4.x, a4.y, a4.z, a4.w};
            float bb[4] = {b4.x, b4.y, b4.z, b4.w};
            #pragma unroll
            for (int i = 0; i < 4; ++i)
                #pragma unroll
                for (int j = 0; j < 4; ++j)
                    acc[i][j] = fmaf(aa[i], bb[j], acc[i][j]);
        }
        __syncthreads();
    }

    #pragma unroll
    for (int i = 0; i < 4; ++i) {
        int m = bm + tr * 4 + i;
        #pragma unroll
        for (int j = 0; j < 4; ++j) {
            int n = bn + tc * 4 + j;
            int b  = m >> 10, s = m & 1023;
            int hh = n >> 6,  d = n & 63;
            C[(((size_t)b * HDIM + hh) * SDIM + s) * HD + d] = acc[i][j];
        }
    }
}

// -- pre: A=[k.k+1], B=[q.k+1], a-vectors (into vb), r6, eta, stat-zero ------
// r17: absorbs eta_kernel (each block computes eta for its 32 tokens x its
// own head; coalesced h reads) and zeroes the (Sum,SumSq) stat buffers
// (blocks 0..15, long before post/gemm7 consume them).
__global__ __launch_bounds__(256) void ab_kernel(
    const float* __restrict__ qb, const float* __restrict__ kb,
    float* __restrict__ vb,            // in: v; out: a = (bw-(v-k))*gw
    const float* __restrict__ ttt_g, const float* __restrict__ ttt_b,
    float* __restrict__ Ab, float* __restrict__ Bb,
    float* __restrict__ r6b,
    const float* __restrict__ h, const float* __restrict__ lr_w,
    const float* __restrict__ lr_b, float* __restrict__ etab,
    float4* __restrict__ stz)
{
    int bh = blockIdx.x >> 5, c = blockIdx.x & 31, cs = c * 32;
    int hh = bh % HDIM, b = bh / HDIM;
    __shared__ float Kc[32][65], Qc[32][65], Vc[32][65];
    __shared__ float ep[32][8];

    if (blockIdx.x < 16) {   // zero 4096 float4 = both stat buffers
        float4 z4; z4.x = z4.y = z4.z = z4.w = 0.f;
        stz[blockIdx.x * 256 + threadIdx.x] = z4;
    }

    // eta partial: 8 threads per token row, 24 h-elems each (coalesced)
    {
        int rg = threadIdx.x >> 3, sl = threadIdx.x & 7;
        const float* hrow = h + ((size_t)b * SDIM + cs + rg) * ADIM + sl * 24;
        float esum = 0.f;
        #pragma unroll
        for (int jj = 0; jj < 24; ++jj)
            esum = fmaf(hrow[jj], lr_w[(sl * 24 + jj) * 3 + hh], esum);
        ep[rg][sl] = esum;
    }

    for (int i = threadIdx.x; i < 2048; i += 256) {
        int t = i >> 6, j = i & 63;
        Kc[t][j] = kb[((size_t)bh * SDIM + cs + t) * HD + j];
        Qc[t][j] = qb[((size_t)bh * SDIM + cs + t) * HD + j];
        Vc[t][j] = vb[((size_t)bh * SDIM + cs + t) * HD + j];
    }
    __syncthreads();

    if (threadIdx.x < 32) {   // finalize eta for this block's 32 tokens
        int t = threadIdx.x;
        float acc = ((ep[t][0] + ep[t][1]) + (ep[t][2] + ep[t][3]))
                  + ((ep[t][4] + ep[t][5]) + (ep[t][6] + ep[t][7]))
                  + lr_b[hh];
        float e = 1.f / (1.f + __expf(-acc)) * (1.f / 64.f);
        etab[(size_t)bh * SDIM + cs + t] = e;
    }

    size_t base = ((size_t)(bh * NCHUNK + c)) * 1024;
    for (int e = threadIdx.x; e < 1024; e += 256) {
        int t = e >> 5, s = e & 31;
        float a = 1.f, bv = 1.f;
        #pragma unroll
        for (int j = 0; j < 64; ++j) {
            float ks = Kc[s][j];
            a  = fmaf(Kc[t][j], ks, a);
            bv = fmaf(Qc[t][j], ks, bv);
        }
        Ab[base + e] = a;
        Bb[base + e] = bv;
    }
    for (int i = threadIdx.x; i < 2048; i += 256) {
        int t = i >> 6, j = i & 63;
        float gwv = ttt_g[hh * 64 + j], bwv = ttt_b[hh * 64 + j];
        float av = fmaf(-(Vc[t][j] - Kc[t][j]), gwv, bwv * gwv);
        Vc[t][j] = av;
        vb[((size_t)bh * SDIM + cs + t) * HD + j] = av;
    }
    __syncthreads();
    if (threadIdx.x < 32) {
        int t = threadIdx.x;
        float acc = 0.f;
        #pragma unroll
        for (int j = 0; j < 64; ++j) acc += Vc[t][j];
        r6b[(size_t)bh * SDIM + cs + t] = acc;
    }
}

// ---------------- staging helper (global -> LDS, float4) -------------------
__device__ __forceinline__ void stage_chunk(
    int pp, int cc, int bh, int idx, int nth,
    const float* __restrict__ kbuf, const float* __restrict__ abuf,
    const float* __restrict__ Ab, const float* __restrict__ etab,
    const float* __restrict__ r6b,
    float4* K4, float4* a4, float4* A4, float2* er6)
{
    const float4* kg = (const float4*)(kbuf + ((size_t)bh * SDIM + cc * 32) * HD);
    const float4* ag = (const float4*)(abuf + ((size_t)bh * SDIM + cc * 32) * HD);
    const float4* Ag = (const float4*)(Ab + ((size_t)(bh * NCHUNK + cc)) * 1024);
    for (int i = idx; i < 512; i += nth) K4[pp * 512 + i] = kg[i];
    for (int i = idx; i < 512; i += nth) a4[pp * 512 + i] = ag[i];
    for (int i = idx; i < 256; i += nth) A4[pp * 256 + i] = Ag[i];
    for (int i = idx; i < 32; i += nth)
        er6[pp * 32 + i] = make_float2(
            etab[(size_t)bh * SDIM + cc * 32 + i] * (1.f / 64.f),
            r6b[(size_t)bh * SDIM + cc * 32 + i]);
}

// ---------------- the sequential TTT scan (12 blocks) — r16 verbatim -------
__global__ __launch_bounds__(256, 1) void ttt_scan(
    const float* __restrict__ kbuf, const float* __restrict__ abuf,
    const float* __restrict__ etab, const float* __restrict__ Ab,
    const float* __restrict__ r6b,
    const float* __restrict__ W1,   const float* __restrict__ b1,
    const float* __restrict__ ttt_g, const float* __restrict__ ttt_b,
    float* __restrict__ Gbuf, float* __restrict__ W0save, float* __restrict__ b0save)
{
    const int bh = blockIdx.x, hh = bh % HDIM;
    const int tid = threadIdx.x, lane = tid & 63;
    const int wv = tid >> 6;
    __shared__ float  Zp[4][16][64];   // 16 KB (slice 0 unused)
    __shared__ float4 K4s[2 * 512];    // 16 KB: K double-buffered
    __shared__ float4 a4s[2 * 512];    // 16 KB: a double-buffered
    __shared__ float4 A4s[2 * 256];    //  8 KB: A double-buffered
    __shared__ float2 er6s[2 * 32];    // 512 B
    __shared__ float  Gl[16][64];      //  4 KB: per-token eta*g (sub-chunk)

    float Wreg[16];
    #pragma unroll
    for (int r = 0; r < 16; ++r)
        Wreg[r] = W1[hh * 4096 + (wv * 16 + r) * 64 + lane];
    float breg = b1[hh * 64 + lane];
    const float gw = ttt_g[hh * 64 + lane];
    const float bw = ttt_b[hh * 64 + lane];
    const float w3 = gw * gw;
    (void)bw;
    const float Cg2 = wave_bcast_sum(w3);
    const float* a_f = (const float*)a4s;

    stage_chunk(0, 0, bh, tid, 256, kbuf, abuf, Ab, etab, r6b,
                K4s, a4s, A4s, er6s);
    __syncthreads();

    for (int c = 0; c < NCHUNK; ++c) {
        const int cs = c * 32;
        const int p = c & 1;

        {
            float* Wd = W0save + ((size_t)(bh * NCHUNK + c)) * 4096
                        + (wv * 16) * 64 + lane;
            #pragma unroll
            for (int r = 0; r < 16; ++r) Wd[r * 64] = Wreg[r];
            if (tid < 64) b0save[(bh * NCHUNK + c) * 64 + tid] = breg;
        }

        #pragma unroll
        for (int h = 0; h < 2; ++h) {
            const int h16 = h * 16, h4 = h * 4;

            // ---- P1 (all waves): Z0 partials for tokens [h16, h16+16) ----
            float Zt[16];
            #pragma unroll
            for (int i = 0; i < 16; ++i) {
                const int t = h16 + i;
                float zt = 0.f;
                #pragma unroll
                for (int r4 = 0; r4 < 4; ++r4) {
                    const float4 kv = K4s[p * 512 + t * 16 + wv * 4 + r4];
                    zt = fmaf(kv.x, Wreg[r4 * 4 + 0], zt);
                    zt = fmaf(kv.y, Wreg[r4 * 4 + 1], zt);
                    zt = fmaf(kv.z, Wreg[r4 * 4 + 2], zt);
                    zt = fmaf(kv.w, Wreg[r4 * 4 + 3], zt);
                }
                Zt[i] = zt;
            }
            if (wv != 0) {
                #pragma unroll
                for (int i = 0; i < 16; ++i)
                    Zp[wv][i][lane] = (wv == 1) ? Zt[i] + breg : Zt[i];
            }
            __syncthreads();   // (A) Zp ready; buffer p staged

            // ---- P2: wave 0 serial; waves 1-3 stage next chunk (h==0) ----
            if (wv == 0) {
                __builtin_amdgcn_s_setprio(1);
                float Z[16];
                #pragma unroll
                for (int i = 0; i < 16; ++i) {
                    float q1 = Zp[1][i][lane], q2 = Zp[2][i][lane],
                          q3 = Zp[3][i][lane];
                    Z[i] = ((Zt[i] + q1) + (q2 + q3));
                }
                float4 avA[4], avB[4];
                float aA, aB; float2 erA, erB;
                #pragma unroll
                for (int q = 0; q < 4; ++q)
                    avA[q] = A4s[p * 256 + h16 * 8 + h4 + q];
                aA  = a_f[p * 2048 + h16 * 64 + lane];
                erA = er6s[p * 32 + h16];
#define TOK(I, avC, aC, erC, avN, aN, erN)                                     \
    {                                                                          \
        if ((I) < 15) {                                                        \
            _Pragma("unroll")                                                  \
            for (int q = ((I) + 2) >> 2; q < 4; ++q)                           \
                avN[q] = A4s[p * 256 + (h16 + (I) + 1) * 8 + h4 + q];          \
            aN  = a_f[p * 2048 + (h16 + (I) + 1) * 64 + lane];                 \
            erN = er6s[p * 32 + h16 + (I) + 1];                                \
        }                                                                      \
        float z  = Z[I];                                                       \
        float a  = aC;                                                         \
        float zg = z * w3;                                                     \
        float x1 = z, x2 = z * z, x3 = zg, x4 = zg * z, x5 = z * a;            \
        red5_asm(x1, x2, x3, x4, x5);                                          \
        float r1 = rl(x1, 63), r2 = rl(x2, 63), r3 = rl(x3, 63);               \
        float r4 = rl(x4, 63), r5 = rl(x5, 63);                                \
        float r6t = (erC).y;                                                   \
        float mu   = r1 * (1.f / 64.f);                                        \
        float var  = fmaf(-mu, mu, r2 * (1.f / 64.f));                         \
        float rstd = fast_rsq(var + EPSLN);                                    \
        float mc   = mu * Cg2;                                                 \
        float sgxh = fmaf(rstd, r3 - mc, r6t);                                 \
        float t4v  = fmaf(mu, mc, fmaf(-2.f * mu, r3, r4));                    \
        float sgz  = fmaf(rstd * rstd, t4v, rstd * (r5 - mu * r6t));           \
        float zh   = (z - mu) * rstd;                                          \
        float gxh  = fmaf(zh, w3, a);                                          \
        float ge   = (fmaf(64.f, gxh, -sgxh) - zh * sgz) * (rstd * (erC).x);   \
        Gl[I][lane] = ge;                                                      \
        _Pragma("unroll")                                                      \
        for (int u = (I) + 1; u < 16; ++u) {                                   \
            const float4 c4 = avC[(u) >> 2]; const int m4 = (u) & 3;           \
            float Atu = (m4 == 0) ? c4.x : (m4 == 1) ? c4.y                    \
                      : (m4 == 2) ? c4.z : c4.w;                               \
            Z[u] = fmaf(-Atu, ge, Z[u]);                                       \
        }                                                                      \
    }
                #pragma unroll
                for (int tp = 0; tp < 8; ++tp) {
                    TOK(2 * tp,     avA, aA, erA, avB, aB, erB)
                    TOK(2 * tp + 1, avB, aB, erB, avA, aA, erA)
                }
#undef TOK
                __builtin_amdgcn_s_setprio(0);
            } else if (h == 0 && c < NCHUNK - 1) {
                stage_chunk(p ^ 1, c + 1, bh, tid - 64, 192,
                            kbuf, abuf, Ab, etab, r6b, K4s, a4s, A4s, er6s);
            }
            __syncthreads();   // (B) Gl ready; staging (h==0) done

            // ---- P3 (all waves): W -= K^T@G ; b -= colsum(G); Gbuf -------
            float btot = 0.f;
            #pragma unroll
            for (int s = 0; s < 16; ++s) {
                float gd = Gl[s][lane];
                btot += gd;
                #pragma unroll
                for (int r4 = 0; r4 < 4; ++r4) {
                    const float4 kv = K4s[p * 512 + (h16 + s) * 16 + wv * 4 + r4];
                    Wreg[r4 * 4 + 0] = fmaf(-kv.x, gd, Wreg[r4 * 4 + 0]);
                    Wreg[r4 * 4 + 1] = fmaf(-kv.y, gd, Wreg[r4 * 4 + 1]);
                    Wreg[r4 * 4 + 2] = fmaf(-kv.z, gd, Wreg[r4 * 4 + 2]);
                    Wreg[r4 * 4 + 3] = fmaf(-kv.w, gd, Wreg[r4 * 4 + 3]);
                }
            }
            breg -= btot;
            {
                float* gb = Gbuf + ((size_t)bh * SDIM + cs + h16) * HD + lane;
                #pragma unroll
                for (int r = 0; r < 4; ++r)
                    gb[(wv * 4 + r) * HD] = Gl[wv * 4 + r][lane];
            }
        }
    }
}

// ---------------- post: Zq = Qc@W0 + b0 - tril(B)@G ; ys = q + ln(Zq) ------
// r17: also accumulates per-row (Sum, SumSq) of ys into ystat (atomics),
// replacing the first lnstats launch.
__global__ __launch_bounds__(256) void post_kernel(
    const float* __restrict__ qbuf, const float* __restrict__ Bb,
    const float* __restrict__ Gbuf, const float* __restrict__ W0save,
    const float* __restrict__ b0save,
    const float* __restrict__ ttt_g, const float* __restrict__ ttt_b,
    float* __restrict__ ys, float2* __restrict__ ystat)
{
    const int bh = blockIdx.x >> 5, c = blockIdx.x & 31, cs = c * 32;
    const int b = bh / HDIM, hh = bh % HDIM;
    const int tid = threadIdx.x, lane = tid & 63, wave = tid >> 6;
    __shared__ float Qc[32][65];
    __shared__ float W0l[64][65];
    __shared__ float Gl[32][64];
    for (int i = tid; i < 2048; i += 256) {
        int t = i >> 6, j = i & 63;
        Qc[t][j] = qbuf[((size_t)bh * SDIM + cs + t) * HD + j];
        Gl[t][j] = Gbuf[((size_t)bh * SDIM + cs + t) * HD + j];
    }
    for (int i = tid; i < 4096; i += 256)
        W0l[i >> 6][i & 63] = W0save[((size_t)(bh * NCHUNK + c)) * 4096 + i];
    __syncthreads();

    const float bb0 = b0save[(bh * NCHUNK + c) * 64 + lane];
    const float gw = ttt_g[hh * 64 + lane], bw = ttt_b[hh * 64 + lane];
    float acc[8];
    #pragma unroll
    for (int r = 0; r < 8; ++r) acc[r] = bb0;
    for (int j = 0; j < 64; ++j) {
        float w0 = W0l[j][lane];
        #pragma unroll
        for (int r = 0; r < 8; ++r)
            acc[r] = fmaf(Qc[wave * 8 + r][j], w0, acc[r]);
    }
    float Breg[8];
    size_t bbase = ((size_t)(bh * NCHUNK + c)) * 1024;
    #pragma unroll
    for (int r = 0; r < 8; ++r)
        Breg[r] = Bb[bbase + (wave * 8 + r) * 32 + (lane & 31)];
    #pragma unroll
    for (int s = 0; s < 32; ++s) {
        float gd = Gl[s][lane];
        #pragma unroll
        for (int r = 0; r < 8; ++r) {
            int t = wave * 8 + r;
            float Bts = rl(Breg[r], s);
            acc[r] = (s <= t) ? fmaf(-Bts, gd, acc[r]) : acc[r];
        }
    }
    #pragma unroll
    for (int r = 0; r < 8; ++r) {
        int t = wave * 8 + r;
        float s1 = wave_bcast_sum(acc[r]);
        float s2 = wave_bcast_sum(acc[r] * acc[r]);
        float mu = s1 * (1.f / 64.f);
        float var = s2 * (1.f / 64.f) - mu * mu;
        float rstd = rsqrtf(var + EPSLN);
        float zh = (acc[r] - mu) * rstd;
        float val = zh * gw + bw + Qc[t][lane];
        ys[((size_t)(b * SDIM) + cs + t) * ADIM + hh * HD + lane] = val;
        float t1 = wave_bcast_sum(val);
        float t2 = wave_bcast_sum(val * val);
        if (lane == 0) {
            atomicAdd(&ystat[(size_t)b * SDIM + cs + t].x, t1);
            atomicAdd(&ystat[(size_t)b * SDIM + cs + t].y, t2);
        }
    }
}

// ---------------- launch ---------------------------------------------------
extern "C" void kernel_launch(void* const* d_in, const int* in_sizes, int n_in,
                              void* d_out, int out_size, void* d_ws, size_t ws_size,
                              hipStream_t stream)
{
    const float* x      = (const float*)d_in[0];
    const float* W_down = (const float*)d_in[1];
    const float* b_down = (const float*)d_in[2];
    const float* Wq     = (const float*)d_in[3];
    const float* Wk     = (const float*)d_in[4];
    const float* Wv     = (const float*)d_in[5];
    const float* Wo     = (const float*)d_in[6];
    const float* W1     = (const float*)d_in[7];
    const float* b1     = (const float*)d_in[8];
    const float* ttt_g  = (const float*)d_in[9];
    const float* ttt_b  = (const float*)d_in[10];
    const float* lr_w   = (const float*)d_in[11];
    const float* lr_b   = (const float*)d_in[12];
    const float* post_g = (const float*)d_in[13];
    const float* post_b = (const float*)d_in[14];
    const float* norm_g = (const float*)d_in[15];
    const float* norm_b = (const float*)d_in[16];
    const float* W_up   = (const float*)d_in[17];
    const float* b_up   = (const float*)d_in[18];
    float* out = (float*)d_out;

    float* ws = (float*)d_ws;
    const size_t SZ = (size_t)MROWS * ADIM;      // 786432
    float* h    = ws;                // [4096][192]
    float* qb   = ws + SZ;           // [12][1024][64]
    float* kb   = ws + 2 * SZ;
    float* vb   = ws + 3 * SZ;       // after ab_kernel: a-vectors
    float* Gb   = ws + 4 * SZ;
    float* etab = ws + 5 * SZ;                       // 12288
    float* Ab   = etab + 12288;                      // 393216
    float* Bb   = Ab + 393216;                       // 393216
    float* W0s  = Bb + 393216;                       // 1572864
    float* b0s  = W0s + 1572864;                     // 24576
    float* r6b  = b0s + 24576;                       // 12288
    float2* ystat = (float2*)(r6b + 12288);          // 4096 float2 (Sum,SumSq)
    float2* tstat = ystat + 4096;                    // 4096 float2
    // aliases (lifetime-disjoint)
    float* ysb  = h;    // post_kernel output (h dead after ab's eta)
    float* tbuf = qb;   // ln(ys)@Wo (qb dead after post_kernel)

    // 1) h = silu(x @ W_down + b_down)
    gemm_k<1, 0, 0, 0><<<dim3(ADIM / 64, MROWS / 64), 256, 0, stream>>>(
        x, W_down, b_down, h, MROWS, ADIM, DDIM,
        nullptr, nullptr, nullptr, nullptr);
    // 2) q,k,v in ONE launch
    gemm_qkv<<<dim3(ADIM / 64, MROWS / 64, 3), 256, 0, stream>>>(
        h, Wq, Wk, Wv, qb);
    // 3) chunk coefficients + a-vectors + r6 + eta + stat-buffer zero
    ab_kernel<<<BDIM * HDIM * NCHUNK, 256, 0, stream>>>(
        qb, kb, vb, ttt_g, ttt_b, Ab, Bb, r6b,
        h, lr_w, lr_b, etab, (float4*)ystat);
    // 4) sequential scan (r16 structure, proven)
    ttt_scan<<<BDIM * HDIM, 256, 0, stream>>>(
        kb, vb, etab, Ab, r6b, W1, b1, ttt_g, ttt_b, Gb, W0s, b0s);
    // 5) outputs ys = q + ln(Zq); accumulates ystat
    post_kernel<<<BDIM * HDIM * NCHUNK, 256, 0, stream>>>(
        qb, Bb, Gb, W0s, b0s, ttt_g, ttt_b, ysb, ystat);
    // 6) t = ln(ys) @ Wo  (LN from ystat; accumulates tstat)
    gemm_k<0, 0, 2, 1><<<dim3(ADIM / 64, MROWS / 64), 256, 0, stream>>>(
        ysb, Wo, nullptr, tbuf, MROWS, ADIM, ADIM,
        ystat, post_g, post_b, tstat);
    // 7) out = ln(t) @ W_up + b_up  (LN from tstat)
    gemm_k<0, 0, 2, 0><<<dim3(DDIM / 64, MROWS / 64), 256, 0, stream>>>(
        tbuf, W_up, b_up, out, MROWS, DDIM, ADIM,
        tstat, norm_g, norm_b, nullptr);
}

// Round 8
// 402.630 us; speedup vs baseline: 1.4270x; 1.1308x over previous
//
#include <hip/hip_runtime.h>
#include <hip/hip_bf16.h>
#include <math.h>

// Problem shape (fixed): B=4, S=1024, D=768, A=192, H=3, hd=64
#define BDIM 4
#define SDIM 1024
#define DDIM 768
#define ADIM 192
#define HDIM 3
#define HD   64
#define MROWS (BDIM*SDIM)      // 4096
#define NCHUNK (SDIM/32)       // 32
#define EPSLN 1e-6f

typedef __attribute__((ext_vector_type(8))) short bf16x8;
typedef __attribute__((ext_vector_type(4))) float f32x4;

// ---------------- DPP wave reduction (64-lane sum, result broadcast) -------
template<int CTRL, int RMASK, bool BC>
__device__ __forceinline__ float dpp_add_step(float x) {
    int t = __builtin_amdgcn_update_dpp(0, __float_as_int(x), CTRL, RMASK, 0xf, BC);
    return x + __int_as_float(t);
}
__device__ __forceinline__ float wave_bcast_sum(float x) {
    x = dpp_add_step<0x111, 0xf, true >(x);
    x = dpp_add_step<0x112, 0xf, true >(x);
    x = dpp_add_step<0x114, 0xf, true >(x);
    x = dpp_add_step<0x118, 0xf, true >(x);
    x = dpp_add_step<0x142, 0xa, false>(x);
    x = dpp_add_step<0x143, 0xc, false>(x);
    return __int_as_float(__builtin_amdgcn_readlane(__float_as_int(x), 63));
}
// 16-lane (DPP-row) suffix sum; lane 15 of each 16-lane row holds the total.
__device__ __forceinline__ float dpp_row16_sum(float x) {
    x = dpp_add_step<0x111, 0xf, true >(x);
    x = dpp_add_step<0x112, 0xf, true >(x);
    x = dpp_add_step<0x114, 0xf, true >(x);
    x = dpp_add_step<0x118, 0xf, true >(x);
    return x;
}
__device__ __forceinline__ float rl(float v, int lane) {
    return __int_as_float(__builtin_amdgcn_readlane(__float_as_int(v), lane));
}
__device__ __forceinline__ float fast_rsq(float x) {
    float r;
    asm("v_rsq_f32 %0, %1" : "=v"(r) : "v"(x));
    return r;
}
// fp32 -> bf16 round-to-nearest-even
__device__ __forceinline__ unsigned short f2bf(float f) {
    unsigned int u = __float_as_uint(f);
    u += 0x7fffu + ((u >> 16) & 1u);
    return (unsigned short)(u >> 16);
}
// 5 simultaneous 64-lane sums via fused DPP adds (validated r7-r10).
__device__ __forceinline__ void red5_asm(float& a, float& b, float& c,
                                         float& d, float& e) {
#define R5_SHR(N)                                                              \
    asm("v_add_f32 %0, %0, %0 row_shr:" #N " row_mask:0xf bank_mask:0xf bound_ctrl:0" : "+v"(a)); \
    asm("v_add_f32 %0, %0, %0 row_shr:" #N " row_mask:0xf bank_mask:0xf bound_ctrl:0" : "+v"(b)); \
    asm("v_add_f32 %0, %0, %0 row_shr:" #N " row_mask:0xf bank_mask:0xf bound_ctrl:0" : "+v"(c)); \
    asm("v_add_f32 %0, %0, %0 row_shr:" #N " row_mask:0xf bank_mask:0xf bound_ctrl:0" : "+v"(d)); \
    asm("v_add_f32 %0, %0, %0 row_shr:" #N " row_mask:0xf bank_mask:0xf bound_ctrl:0" : "+v"(e));
#define R5_BC(N, RM)                                                           \
    asm("v_add_f32 %0, %0, %0 row_bcast:" #N " row_mask:" #RM " bank_mask:0xf" : "+v"(a)); \
    asm("v_add_f32 %0, %0, %0 row_bcast:" #N " row_mask:" #RM " bank_mask:0xf" : "+v"(b)); \
    asm("v_add_f32 %0, %0, %0 row_bcast:" #N " row_mask:" #RM " bank_mask:0xf" : "+v"(c)); \
    asm("v_add_f32 %0, %0, %0 row_bcast:" #N " row_mask:" #RM " bank_mask:0xf" : "+v"(d)); \
    asm("v_add_f32 %0, %0, %0 row_bcast:" #N " row_mask:" #RM " bank_mask:0xf" : "+v"(e));
    R5_SHR(1) R5_SHR(2) R5_SHR(4) R5_SHR(8)
    R5_BC(15, 0xa) R5_BC(31, 0xc)
#undef R5_SHR
#undef R5_BC
}

// ------ weight pre-pass: out[n][k] = bf16(in[k][n]), tiled transpose -------
__global__ __launch_bounds__(256) void wconv(
    const float* __restrict__ w0, unsigned short* __restrict__ o0,
    const float* __restrict__ w1, unsigned short* __restrict__ o1,
    const float* __restrict__ w2, unsigned short* __restrict__ o2,
    const float* __restrict__ w3, unsigned short* __restrict__ o3,
    const float* __restrict__ w4, unsigned short* __restrict__ o4,
    const float* __restrict__ w5, unsigned short* __restrict__ o5)
{
    int z = blockIdx.z;
    const float* in; unsigned short* outp; int K, N;
    if      (z == 0) { in = w0; outp = o0; K = DDIM; N = ADIM; }
    else if (z == 1) { in = w1; outp = o1; K = ADIM; N = ADIM; }
    else if (z == 2) { in = w2; outp = o2; K = ADIM; N = ADIM; }
    else if (z == 3) { in = w3; outp = o3; K = ADIM; N = ADIM; }
    else if (z == 4) { in = w4; outp = o4; K = ADIM; N = ADIM; }
    else             { in = w5; outp = o5; K = ADIM; N = DDIM; }
    int bk = blockIdx.x * 32, bn = blockIdx.y * 32;
    if (bk >= K || bn >= N) return;
    __shared__ float t[32][33];
    int tk = threadIdx.x & 31, tn = threadIdx.x >> 5;   // 32 x 8
    #pragma unroll
    for (int r = 0; r < 4; ++r)
        t[tn + r * 8][tk] = in[(size_t)(bk + tn + r * 8) * N + bn + tk];
    __syncthreads();
    #pragma unroll
    for (int r = 0; r < 4; ++r)
        outp[(size_t)(bn + tn + r * 8) * K + bk + tk] = f2bf(t[tk][tn + r * 8]);
}

// ---------------- bf16-MFMA tiled GEMM: C = act(lnA(A) @ B + bias) ---------
// A fp32 [M][K]; Bt bf16 TRANSPOSED [N][K]. 64x64 block tile, 4 waves (2x2),
// each wave 32x32 via 2x2 mfma_f32_16x16x32_bf16. A converted RNE at staging.
// LNA: 0 plain; 2 = LayerNorm A from raw (Sum,SumSq) stats.
// STATS: accumulate per-row (Sum,SumSq) of output into ostat (atomics).
template<int ACT, int LAYOUT, int LNA, int STATS>
__global__ __launch_bounds__(256) void gemm_k(
    const float* __restrict__ A, const unsigned short* __restrict__ Bt,
    const float* __restrict__ bias, float* __restrict__ C,
    int M, int N, int K,
    const float2* __restrict__ lnst, const float* __restrict__ lng,
    const float* __restrict__ lnbb, float2* __restrict__ ostat)
{
    __shared__ unsigned short As[64][40];   // +8 pad: 80B rows, 16B-aligned
    __shared__ unsigned short Bs[64][40];
    __shared__ float2 lst[64];
    const int tid = threadIdx.x;
    const int bm = blockIdx.y * 64, bn = blockIdx.x * 64;
    const int lane = tid & 63, wv = tid >> 6;
    const int wr = wv >> 1, wc = wv & 1;
    const int l15 = lane & 15, l4 = lane >> 4;
    f32x4 acc[2][2] = {};

    if (LNA == 2) {
        if (tid < 64) {
            float2 s = lnst[bm + tid];
            float mu = s.x * (1.f / 192.f);
            float var = fmaf(-mu, mu, s.y * (1.f / 192.f));
            lst[tid] = make_float2(mu, rsqrtf(var + EPSLN));
        }
        __syncthreads();
    }

    const int sm = tid >> 2;          // 0..63 staging row
    const int sk = (tid & 3) * 8;     // k-segment (8 elems)
    for (int k0 = 0; k0 < K; k0 += 32) {
        {   // A: fp32 -> (LN) -> bf16
            const float* ap = A + (size_t)(bm + sm) * K + k0 + sk;
            float4 a0 = *(const float4*)ap;
            float4 a1 = *(const float4*)(ap + 4);
            float av[8] = {a0.x, a0.y, a0.z, a0.w, a1.x, a1.y, a1.z, a1.w};
            if (LNA == 2) {
                float2 stv = lst[sm];
                #pragma unroll
                for (int e = 0; e < 8; ++e)
                    av[e] = fmaf((av[e] - stv.x) * stv.y,
                                 lng[k0 + sk + e], lnbb[k0 + sk + e]);
            }
            uint4 w;
            w.x = (unsigned)f2bf(av[0]) | ((unsigned)f2bf(av[1]) << 16);
            w.y = (unsigned)f2bf(av[2]) | ((unsigned)f2bf(av[3]) << 16);
            w.z = (unsigned)f2bf(av[4]) | ((unsigned)f2bf(av[5]) << 16);
            w.w = (unsigned)f2bf(av[6]) | ((unsigned)f2bf(av[7]) << 16);
            *(uint4*)&As[sm][sk] = w;
        }
        {   // B: straight 16B bf16 copy (already transposed+converted)
            *(uint4*)&Bs[sm][sk] =
                *(const uint4*)(Bt + (size_t)(bn + sm) * K + k0 + sk);
        }
        __syncthreads();
        bf16x8 af0 = *(const bf16x8*)&As[wr * 32 + l15][l4 * 8];
        bf16x8 af1 = *(const bf16x8*)&As[wr * 32 + 16 + l15][l4 * 8];
        bf16x8 bf0 = *(const bf16x8*)&Bs[wc * 32 + l15][l4 * 8];
        bf16x8 bf1 = *(const bf16x8*)&Bs[wc * 32 + 16 + l15][l4 * 8];
        acc[0][0] = __builtin_amdgcn_mfma_f32_16x16x32_bf16(af0, bf0, acc[0][0], 0, 0, 0);
        acc[0][1] = __builtin_amdgcn_mfma_f32_16x16x32_bf16(af0, bf1, acc[0][1], 0, 0, 0);
        acc[1][0] = __builtin_amdgcn_mfma_f32_16x16x32_bf16(af1, bf0, acc[1][0], 0, 0, 0);
        acc[1][1] = __builtin_amdgcn_mfma_f32_16x16x32_bf16(af1, bf1, acc[1][1], 0, 0, 0);
        __syncthreads();
    }

    float rs1[2][4] = {}, rs2[2][4] = {};
    #pragma unroll
    for (int rt = 0; rt < 2; ++rt) {
        #pragma unroll
        for (int ct = 0; ct < 2; ++ct) {
            #pragma unroll
            for (int r = 0; r < 4; ++r) {
                int m = bm + wr * 32 + rt * 16 + l4 * 4 + r;
                int n = bn + wc * 32 + ct * 16 + l15;
                float v = acc[rt][ct][r];
                if (bias) v += bias[n];
                if (ACT == 1) v = v / (1.f + __expf(-v));   // silu
                if (STATS) { rs1[rt][r] += v; rs2[rt][r] = fmaf(v, v, rs2[rt][r]); }
                if (LAYOUT == 0) {
                    C[(size_t)m * N + n] = v;
                } else {
                    int b  = m >> 10, s = m & 1023;
                    int hh = n >> 6,  d = n & 63;
                    C[(((size_t)b * HDIM + hh) * SDIM + s) * HD + d] = v;
                }
            }
        }
    }
    if (STATS) {
        #pragma unroll
        for (int rt = 0; rt < 2; ++rt)
            #pragma unroll
            for (int r = 0; r < 4; ++r) {
                float s1 = dpp_row16_sum(rs1[rt][r]);
                float s2 = dpp_row16_sum(rs2[rt][r]);
                if (l15 == 15) {
                    int m = bm + wr * 32 + rt * 16 + l4 * 4 + r;
                    atomicAdd(&ostat[m].x, s1);
                    atomicAdd(&ostat[m].y, s2);
                }
            }
    }
}

// ---------------- fused QKV MFMA GEMM: blockIdx.z picks the head -----------
__global__ __launch_bounds__(256) void gemm_qkv(
    const float* __restrict__ A, const unsigned short* __restrict__ BTq,
    const unsigned short* __restrict__ BTk, const unsigned short* __restrict__ BTv,
    float* __restrict__ Cbase)
{
    const unsigned short* Bt = (blockIdx.z == 0) ? BTq
                              : (blockIdx.z == 1) ? BTk : BTv;
    float* C = Cbase + (size_t)blockIdx.z * ((size_t)MROWS * ADIM);
    __shared__ unsigned short As[64][40];
    __shared__ unsigned short Bs[64][40];
    const int tid = threadIdx.x;
    const int bm = blockIdx.y * 64, bn = blockIdx.x * 64;
    const int lane = tid & 63, wv = tid >> 6;
    const int wr = wv >> 1, wc = wv & 1;
    const int l15 = lane & 15, l4 = lane >> 4;
    f32x4 acc[2][2] = {};

    const int sm = tid >> 2;
    const int sk = (tid & 3) * 8;
    for (int k0 = 0; k0 < ADIM; k0 += 32) {
        {
            const float* ap = A + (size_t)(bm + sm) * ADIM + k0 + sk;
            float4 a0 = *(const float4*)ap;
            float4 a1 = *(const float4*)(ap + 4);
            uint4 w;
            w.x = (unsigned)f2bf(a0.x) | ((unsigned)f2bf(a0.y) << 16);
            w.y = (unsigned)f2bf(a0.z) | ((unsigned)f2bf(a0.w) << 16);
            w.z = (unsigned)f2bf(a1.x) | ((unsigned)f2bf(a1.y) << 16);
            w.w = (unsigned)f2bf(a1.z) | ((unsigned)f2bf(a1.w) << 16);
            *(uint4*)&As[sm][sk] = w;
        }
        *(uint4*)&Bs[sm][sk] =
            *(const uint4*)(Bt + (size_t)(bn + sm) * ADIM + k0 + sk);
        __syncthreads();
        bf16x8 af0 = *(const bf16x8*)&As[wr * 32 + l15][l4 * 8];
        bf16x8 af1 = *(const bf16x8*)&As[wr * 32 + 16 + l15][l4 * 8];
        bf16x8 bf0 = *(const bf16x8*)&Bs[wc * 32 + l15][l4 * 8];
        bf16x8 bf1 = *(const bf16x8*)&Bs[wc * 32 + 16 + l15][l4 * 8];
        acc[0][0] = __builtin_amdgcn_mfma_f32_16x16x32_bf16(af0, bf0, acc[0][0], 0, 0, 0);
        acc[0][1] = __builtin_amdgcn_mfma_f32_16x16x32_bf16(af0, bf1, acc[0][1], 0, 0, 0);
        acc[1][0] = __builtin_amdgcn_mfma_f32_16x16x32_bf16(af1, bf0, acc[1][0], 0, 0, 0);
        acc[1][1] = __builtin_amdgcn_mfma_f32_16x16x32_bf16(af1, bf1, acc[1][1], 0, 0, 0);
        __syncthreads();
    }

    #pragma unroll
    for (int rt = 0; rt < 2; ++rt)
        #pragma unroll
        for (int ct = 0; ct < 2; ++ct)
            #pragma unroll
            for (int r = 0; r < 4; ++r) {
                int m = bm + wr * 32 + rt * 16 + l4 * 4 + r;
                int n = bn + wc * 32 + ct * 16 + l15;
                int b  = m >> 10, s = m & 1023;
                int hh = n >> 6,  d = n & 63;
                C[(((size_t)b * HDIM + hh) * SDIM + s) * HD + d] = acc[rt][ct][r];
            }
}

// -- pre: A=[k.k+1], B=[q.k+1], a-vectors (into vb), r6, eta, stat-zero ------
__global__ __launch_bounds__(256) void ab_kernel(
    const float* __restrict__ qb, const float* __restrict__ kb,
    float* __restrict__ vb,            // in: v; out: a = (bw-(v-k))*gw
    const float* __restrict__ ttt_g, const float* __restrict__ ttt_b,
    float* __restrict__ Ab, float* __restrict__ Bb,
    float* __restrict__ r6b,
    const float* __restrict__ h, const float* __restrict__ lr_w,
    const float* __restrict__ lr_b, float* __restrict__ etab,
    float4* __restrict__ stz)
{
    int bh = blockIdx.x >> 5, c = blockIdx.x & 31, cs = c * 32;
    int hh = bh % HDIM, b = bh / HDIM;
    __shared__ float Kc[32][65], Qc[32][65], Vc[32][65];
    __shared__ float ep[32][8];

    if (blockIdx.x < 16) {   // zero 4096 float4 = both stat buffers
        float4 z4; z4.x = z4.y = z4.z = z4.w = 0.f;
        stz[blockIdx.x * 256 + threadIdx.x] = z4;
    }

    // eta partial: 8 threads per token row, 24 h-elems each (coalesced)
    {
        int rg = threadIdx.x >> 3, sl = threadIdx.x & 7;
        const float* hrow = h + ((size_t)b * SDIM + cs + rg) * ADIM + sl * 24;
        float esum = 0.f;
        #pragma unroll
        for (int jj = 0; jj < 24; ++jj)
            esum = fmaf(hrow[jj], lr_w[(sl * 24 + jj) * 3 + hh], esum);
        ep[rg][sl] = esum;
    }

    for (int i = threadIdx.x; i < 2048; i += 256) {
        int t = i >> 6, j = i & 63;
        Kc[t][j] = kb[((size_t)bh * SDIM + cs + t) * HD + j];
        Qc[t][j] = qb[((size_t)bh * SDIM + cs + t) * HD + j];
        Vc[t][j] = vb[((size_t)bh * SDIM + cs + t) * HD + j];
    }
    __syncthreads();

    if (threadIdx.x < 32) {   // finalize eta for this block's 32 tokens
        int t = threadIdx.x;
        float acc = ((ep[t][0] + ep[t][1]) + (ep[t][2] + ep[t][3]))
                  + ((ep[t][4] + ep[t][5]) + (ep[t][6] + ep[t][7]))
                  + lr_b[hh];
        float e = 1.f / (1.f + __expf(-acc)) * (1.f / 64.f);
        etab[(size_t)bh * SDIM + cs + t] = e;
    }

    size_t base = ((size_t)(bh * NCHUNK + c)) * 1024;
    for (int e = threadIdx.x; e < 1024; e += 256) {
        int t = e >> 5, s = e & 31;
        float a = 1.f, bv = 1.f;
        #pragma unroll
        for (int j = 0; j < 64; ++j) {
            float ks = Kc[s][j];
            a  = fmaf(Kc[t][j], ks, a);
            bv = fmaf(Qc[t][j], ks, bv);
        }
        Ab[base + e] = a;
        Bb[base + e] = bv;
    }
    for (int i = threadIdx.x; i < 2048; i += 256) {
        int t = i >> 6, j = i & 63;
        float gwv = ttt_g[hh * 64 + j], bwv = ttt_b[hh * 64 + j];
        float av = fmaf(-(Vc[t][j] - Kc[t][j]), gwv, bwv * gwv);
        Vc[t][j] = av;
        vb[((size_t)bh * SDIM + cs + t) * HD + j] = av;
    }
    __syncthreads();
    if (threadIdx.x < 32) {
        int t = threadIdx.x;
        float acc = 0.f;
        #pragma unroll
        for (int j = 0; j < 64; ++j) acc += Vc[t][j];
        r6b[(size_t)bh * SDIM + cs + t] = acc;
    }
}

// ---------------- staging helper (global -> LDS, float4) -------------------
__device__ __forceinline__ void stage_chunk(
    int pp, int cc, int bh, int idx, int nth,
    const float* __restrict__ kbuf, const float* __restrict__ abuf,
    const float* __restrict__ Ab, const float* __restrict__ etab,
    const float* __restrict__ r6b,
    float4* K4, float4* a4, float4* A4, float2* er6)
{
    const float4* kg = (const float4*)(kbuf + ((size_t)bh * SDIM + cc * 32) * HD);
    const float4* ag = (const float4*)(abuf + ((size_t)bh * SDIM + cc * 32) * HD);
    const float4* Ag = (const float4*)(Ab + ((size_t)(bh * NCHUNK + cc)) * 1024);
    for (int i = idx; i < 512; i += nth) K4[pp * 512 + i] = kg[i];
    for (int i = idx; i < 512; i += nth) a4[pp * 512 + i] = ag[i];
    for (int i = idx; i < 256; i += nth) A4[pp * 256 + i] = Ag[i];
    for (int i = idx; i < 32; i += nth)
        er6[pp * 32 + i] = make_float2(
            etab[(size_t)bh * SDIM + cc * 32 + i] * (1.f / 64.f),
            r6b[(size_t)bh * SDIM + cc * 32 + i]);
}

// ---------------- the sequential TTT scan (12 blocks) — r16 verbatim -------
__global__ __launch_bounds__(256, 1) void ttt_scan(
    const float* __restrict__ kbuf, const float* __restrict__ abuf,
    const float* __restrict__ etab, const float* __restrict__ Ab,
    const float* __restrict__ r6b,
    const float* __restrict__ W1,   const float* __restrict__ b1,
    const float* __restrict__ ttt_g, const float* __restrict__ ttt_b,
    float* __restrict__ Gbuf, float* __restrict__ W0save, float* __restrict__ b0save)
{
    const int bh = blockIdx.x, hh = bh % HDIM;
    const int tid = threadIdx.x, lane = tid & 63;
    const int wv = tid >> 6;
    __shared__ float  Zp[4][16][64];   // 16 KB (slice 0 unused)
    __shared__ float4 K4s[2 * 512];    // 16 KB: K double-buffered
    __shared__ float4 a4s[2 * 512];    // 16 KB: a double-buffered
    __shared__ float4 A4s[2 * 256];    //  8 KB: A double-buffered
    __shared__ float2 er6s[2 * 32];    // 512 B
    __shared__ float  Gl[16][64];      //  4 KB: per-token eta*g (sub-chunk)

    float Wreg[16];
    #pragma unroll
    for (int r = 0; r < 16; ++r)
        Wreg[r] = W1[hh * 4096 + (wv * 16 + r) * 64 + lane];
    float breg = b1[hh * 64 + lane];
    const float gw = ttt_g[hh * 64 + lane];
    const float bw = ttt_b[hh * 64 + lane];
    const float w3 = gw * gw;
    (void)bw;
    const float Cg2 = wave_bcast_sum(w3);
    const float* a_f = (const float*)a4s;

    stage_chunk(0, 0, bh, tid, 256, kbuf, abuf, Ab, etab, r6b,
                K4s, a4s, A4s, er6s);
    __syncthreads();

    for (int c = 0; c < NCHUNK; ++c) {
        const int cs = c * 32;
        const int p = c & 1;

        {
            float* Wd = W0save + ((size_t)(bh * NCHUNK + c)) * 4096
                        + (wv * 16) * 64 + lane;
            #pragma unroll
            for (int r = 0; r < 16; ++r) Wd[r * 64] = Wreg[r];
            if (tid < 64) b0save[(bh * NCHUNK + c) * 64 + tid] = breg;
        }

        #pragma unroll
        for (int h = 0; h < 2; ++h) {
            const int h16 = h * 16, h4 = h * 4;

            // ---- P1 (all waves): Z0 partials for tokens [h16, h16+16) ----
            float Zt[16];
            #pragma unroll
            for (int i = 0; i < 16; ++i) {
                const int t = h16 + i;
                float zt = 0.f;
                #pragma unroll
                for (int r4 = 0; r4 < 4; ++r4) {
                    const float4 kv = K4s[p * 512 + t * 16 + wv * 4 + r4];
                    zt = fmaf(kv.x, Wreg[r4 * 4 + 0], zt);
                    zt = fmaf(kv.y, Wreg[r4 * 4 + 1], zt);
                    zt = fmaf(kv.z, Wreg[r4 * 4 + 2], zt);
                    zt = fmaf(kv.w, Wreg[r4 * 4 + 3], zt);
                }
                Zt[i] = zt;
            }
            if (wv != 0) {
                #pragma unroll
                for (int i = 0; i < 16; ++i)
                    Zp[wv][i][lane] = (wv == 1) ? Zt[i] + breg : Zt[i];
            }
            __syncthreads();   // (A) Zp ready; buffer p staged

            // ---- P2: wave 0 serial; waves 1-3 stage next chunk (h==0) ----
            if (wv == 0) {
                __builtin_amdgcn_s_setprio(1);
                float Z[16];
                #pragma unroll
                for (int i = 0; i < 16; ++i) {
                    float q1 = Zp[1][i][lane], q2 = Zp[2][i][lane],
                          q3 = Zp[3][i][lane];
                    Z[i] = ((Zt[i] + q1) + (q2 + q3));
                }
                float4 avA[4], avB[4];
                float aA, aB; float2 erA, erB;
                #pragma unroll
                for (int q = 0; q < 4; ++q)
                    avA[q] = A4s[p * 256 + h16 * 8 + h4 + q];
                aA  = a_f[p * 2048 + h16 * 64 + lane];
                erA = er6s[p * 32 + h16];
#define TOK(I, avC, aC, erC, avN, aN, erN)                                     \
    {                                                                          \
        if ((I) < 15) {                                                        \
            _Pragma("unroll")                                                  \
            for (int q = ((I) + 2) >> 2; q < 4; ++q)                           \
                avN[q] = A4s[p * 256 + (h16 + (I) + 1) * 8 + h4 + q];          \
            aN  = a_f[p * 2048 + (h16 + (I) + 1) * 64 + lane];                 \
            erN = er6s[p * 32 + h16 + (I) + 1];                                \
        }                                                                      \
        float z  = Z[I];                                                       \
        float a  = aC;                                                         \
        float zg = z * w3;                                                     \
        float x1 = z, x2 = z * z, x3 = zg, x4 = zg * z, x5 = z * a;            \
        red5_asm(x1, x2, x3, x4, x5);                                          \
        float r1 = rl(x1, 63), r2 = rl(x2, 63), r3 = rl(x3, 63);               \
        float r4 = rl(x4, 63), r5 = rl(x5, 63);                                \
        float r6t = (erC).y;                                                   \
        float mu   = r1 * (1.f / 64.f);                                        \
        float var  = fmaf(-mu, mu, r2 * (1.f / 64.f));                         \
        float rstd = fast_rsq(var + EPSLN);                                    \
        float mc   = mu * Cg2;                                                 \
        float sgxh = fmaf(rstd, r3 - mc, r6t);                                 \
        float t4v  = fmaf(mu, mc, fmaf(-2.f * mu, r3, r4));                    \
        float sgz  = fmaf(rstd * rstd, t4v, rstd * (r5 - mu * r6t));           \
        float zh   = (z - mu) * rstd;                                          \
        float gxh  = fmaf(zh, w3, a);                                          \
        float ge   = (fmaf(64.f, gxh, -sgxh) - zh * sgz) * (rstd * (erC).x);   \
        Gl[I][lane] = ge;                                                      \
        _Pragma("unroll")                                                      \
        for (int u = (I) + 1; u < 16; ++u) {                                   \
            const float4 c4 = avC[(u) >> 2]; const int m4 = (u) & 3;           \
            float Atu = (m4 == 0) ? c4.x : (m4 == 1) ? c4.y                    \
                      : (m4 == 2) ? c4.z : c4.w;                               \
            Z[u] = fmaf(-Atu, ge, Z[u]);                                       \
        }                                                                      \
    }
                #pragma unroll
                for (int tp = 0; tp < 8; ++tp) {
                    TOK(2 * tp,     avA, aA, erA, avB, aB, erB)
                    TOK(2 * tp + 1, avB, aB, erB, avA, aA, erA)
                }
#undef TOK
                __builtin_amdgcn_s_setprio(0);
            } else if (h == 0 && c < NCHUNK - 1) {
                stage_chunk(p ^ 1, c + 1, bh, tid - 64, 192,
                            kbuf, abuf, Ab, etab, r6b, K4s, a4s, A4s, er6s);
            }
            __syncthreads();   // (B) Gl ready; staging (h==0) done

            // ---- P3 (all waves): W -= K^T@G ; b -= colsum(G); Gbuf -------
            float btot = 0.f;
            #pragma unroll
            for (int s = 0; s < 16; ++s) {
                float gd = Gl[s][lane];
                btot += gd;
                #pragma unroll
                for (int r4 = 0; r4 < 4; ++r4) {
                    const float4 kv = K4s[p * 512 + (h16 + s) * 16 + wv * 4 + r4];
                    Wreg[r4 * 4 + 0] = fmaf(-kv.x, gd, Wreg[r4 * 4 + 0]);
                    Wreg[r4 * 4 + 1] = fmaf(-kv.y, gd, Wreg[r4 * 4 + 1]);
                    Wreg[r4 * 4 + 2] = fmaf(-kv.z, gd, Wreg[r4 * 4 + 2]);
                    Wreg[r4 * 4 + 3] = fmaf(-kv.w, gd, Wreg[r4 * 4 + 3]);
                }
            }
            breg -= btot;
            {
                float* gb = Gbuf + ((size_t)bh * SDIM + cs + h16) * HD + lane;
                #pragma unroll
                for (int r = 0; r < 4; ++r)
                    gb[(wv * 4 + r) * HD] = Gl[wv * 4 + r][lane];
            }
        }
    }
}

// ---------------- post: Zq = Qc@W0 + b0 - tril(B)@G ; ys = q + ln(Zq) ------
__global__ __launch_bounds__(256) void post_kernel(
    const float* __restrict__ qbuf, const float* __restrict__ Bb,
    const float* __restrict__ Gbuf, const float* __restrict__ W0save,
    const float* __restrict__ b0save,
    const float* __restrict__ ttt_g, const float* __restrict__ ttt_b,
    float* __restrict__ ys, float2* __restrict__ ystat)
{
    const int bh = blockIdx.x >> 5, c = blockIdx.x & 31, cs = c * 32;
    const int b = bh / HDIM, hh = bh % HDIM;
    const int tid = threadIdx.x, lane = tid & 63, wave = tid >> 6;
    __shared__ float Qc[32][65];
    __shared__ float W0l[64][65];
    __shared__ float Gl[32][64];
    for (int i = tid; i < 2048; i += 256) {
        int t = i >> 6, j = i & 63;
        Qc[t][j] = qbuf[((size_t)bh * SDIM + cs + t) * HD + j];
        Gl[t][j] = Gbuf[((size_t)bh * SDIM + cs + t) * HD + j];
    }
    for (int i = tid; i < 4096; i += 256)
        W0l[i >> 6][i & 63] = W0save[((size_t)(bh * NCHUNK + c)) * 4096 + i];
    __syncthreads();

    const float bb0 = b0save[(bh * NCHUNK + c) * 64 + lane];
    const float gw = ttt_g[hh * 64 + lane], bw = ttt_b[hh * 64 + lane];
    float acc[8];
    #pragma unroll
    for (int r = 0; r < 8; ++r) acc[r] = bb0;
    for (int j = 0; j < 64; ++j) {
        float w0 = W0l[j][lane];
        #pragma unroll
        for (int r = 0; r < 8; ++r)
            acc[r] = fmaf(Qc[wave * 8 + r][j], w0, acc[r]);
    }
    float Breg[8];
    size_t bbase = ((size_t)(bh * NCHUNK + c)) * 1024;
    #pragma unroll
    for (int r = 0; r < 8; ++r)
        Breg[r] = Bb[bbase + (wave * 8 + r) * 32 + (lane & 31)];
    #pragma unroll
    for (int s = 0; s < 32; ++s) {
        float gd = Gl[s][lane];
        #pragma unroll
        for (int r = 0; r < 8; ++r) {
            int t = wave * 8 + r;
            float Bts = rl(Breg[r], s);
            acc[r] = (s <= t) ? fmaf(-Bts, gd, acc[r]) : acc[r];
        }
    }
    #pragma unroll
    for (int r = 0; r < 8; ++r) {
        int t = wave * 8 + r;
        float s1 = wave_bcast_sum(acc[r]);
        float s2 = wave_bcast_sum(acc[r] * acc[r]);
        float mu = s1 * (1.f / 64.f);
        float var = s2 * (1.f / 64.f) - mu * mu;
        float rstd = rsqrtf(var + EPSLN);
        float zh = (acc[r] - mu) * rstd;
        float val = zh * gw + bw + Qc[t][lane];
        ys[((size_t)(b * SDIM) + cs + t) * ADIM + hh * HD + lane] = val;
        float t1 = wave_bcast_sum(val);
        float t2 = wave_bcast_sum(val * val);
        if (lane == 0) {
            atomicAdd(&ystat[(size_t)b * SDIM + cs + t].x, t1);
            atomicAdd(&ystat[(size_t)b * SDIM + cs + t].y, t2);
        }
    }
}

// ---------------- launch ---------------------------------------------------
extern "C" void kernel_launch(void* const* d_in, const int* in_sizes, int n_in,
                              void* d_out, int out_size, void* d_ws, size_t ws_size,
                              hipStream_t stream)
{
    const float* x      = (const float*)d_in[0];
    const float* W_down = (const float*)d_in[1];
    const float* b_down = (const float*)d_in[2];
    const float* Wq     = (const float*)d_in[3];
    const float* Wk     = (const float*)d_in[4];
    const float* Wv     = (const float*)d_in[5];
    const float* Wo     = (const float*)d_in[6];
    const float* W1     = (const float*)d_in[7];
    const float* b1     = (const float*)d_in[8];
    const float* ttt_g  = (const float*)d_in[9];
    const float* ttt_b  = (const float*)d_in[10];
    const float* lr_w   = (const float*)d_in[11];
    const float* lr_b   = (const float*)d_in[12];
    const float* post_g = (const float*)d_in[13];
    const float* post_b = (const float*)d_in[14];
    const float* norm_g = (const float*)d_in[15];
    const float* norm_b = (const float*)d_in[16];
    const float* W_up   = (const float*)d_in[17];
    const float* b_up   = (const float*)d_in[18];
    float* out = (float*)d_out;

    float* ws = (float*)d_ws;
    const size_t SZ = (size_t)MROWS * ADIM;      // 786432
    float* h    = ws;                // [4096][192]
    float* qb   = ws + SZ;           // [12][1024][64]
    float* kb   = ws + 2 * SZ;
    float* vb   = ws + 3 * SZ;       // after ab_kernel: a-vectors
    float* Gb   = ws + 4 * SZ;
    float* etab = ws + 5 * SZ;                       // 12288
    float* Ab   = etab + 12288;                      // 393216
    float* Bb   = Ab + 393216;                       // 393216
    float* W0s  = Bb + 393216;                       // 1572864
    float* b0s  = W0s + 1572864;                     // 24576
    float* r6b  = b0s + 24576;                       // 12288
    float2* ystat = (float2*)(r6b + 12288);          // 4096 float2 (Sum,SumSq)
    float2* tstat = ystat + 4096;                    // 4096 float2
    unsigned short* WdT = (unsigned short*)(tstat + 4096);  // [192][768] bf16
    unsigned short* WqT = WdT + 147456;              // [192][192]
    unsigned short* WkT = WqT + 36864;
    unsigned short* WvT = WkT + 36864;
    unsigned short* WoT = WvT + 36864;
    unsigned short* WuT = WoT + 36864;               // [768][192]
    // aliases (lifetime-disjoint)
    float* ysb  = h;    // post_kernel output (h dead after ab's eta)
    float* tbuf = qb;   // ln(ys)@Wo (qb dead after post_kernel)

    // 0) weights -> bf16 transposed (once per invocation, ~2us)
    wconv<<<dim3(24, 24, 6), 256, 0, stream>>>(
        W_down, WdT, Wq, WqT, Wk, WkT, Wv, WvT, Wo, WoT, W_up, WuT);
    // 1) h = silu(x @ W_down + b_down)   [MFMA]
    gemm_k<1, 0, 0, 0><<<dim3(ADIM / 64, MROWS / 64), 256, 0, stream>>>(
        x, WdT, b_down, h, MROWS, ADIM, DDIM,
        nullptr, nullptr, nullptr, nullptr);
    // 2) q,k,v in ONE launch   [MFMA]
    gemm_qkv<<<dim3(ADIM / 64, MROWS / 64, 3), 256, 0, stream>>>(
        h, WqT, WkT, WvT, qb);
    // 3) chunk coefficients + a-vectors + r6 + eta + stat-buffer zero
    ab_kernel<<<BDIM * HDIM * NCHUNK, 256, 0, stream>>>(
        qb, kb, vb, ttt_g, ttt_b, Ab, Bb, r6b,
        h, lr_w, lr_b, etab, (float4*)ystat);
    // 4) sequential scan (r16 structure, proven)
    ttt_scan<<<BDIM * HDIM, 256, 0, stream>>>(
        kb, vb, etab, Ab, r6b, W1, b1, ttt_g, ttt_b, Gb, W0s, b0s);
    // 5) outputs ys = q + ln(Zq); accumulates ystat
    post_kernel<<<BDIM * HDIM * NCHUNK, 256, 0, stream>>>(
        qb, Bb, Gb, W0s, b0s, ttt_g, ttt_b, ysb, ystat);
    // 6) t = ln(ys) @ Wo  [MFMA; LN from ystat; accumulates tstat]
    gemm_k<0, 0, 2, 1><<<dim3(ADIM / 64, MROWS / 64), 256, 0, stream>>>(
        ysb, WoT, nullptr, tbuf, MROWS, ADIM, ADIM,
        ystat, post_g, post_b, tstat);
    // 7) out = ln(t) @ W_up + b_up  [MFMA; LN from tstat]
    gemm_k<0, 0, 2, 0><<<dim3(DDIM / 64, MROWS / 64), 256, 0, stream>>>(
        tbuf, WuT, b_up, out, MROWS, DDIM, ADIM,
        tstat, norm_g, norm_b, nullptr);
}

// Round 9
// 400.866 us; speedup vs baseline: 1.4333x; 1.0044x over previous
//
#include <hip/hip_runtime.h>
#include <hip/hip_bf16.h>
#include <math.h>

// Problem shape (fixed): B=4, S=1024, D=768, A=192, H=3, hd=64
#define BDIM 4
#define SDIM 1024
#define DDIM 768
#define ADIM 192
#define HDIM 3
#define HD   64
#define MROWS (BDIM*SDIM)      // 4096
#define NCHUNK (SDIM/32)       // 32
#define EPSLN 1e-6f

typedef __attribute__((ext_vector_type(8))) short bf16x8;
typedef __attribute__((ext_vector_type(4))) float f32x4;

// ---------------- DPP wave reduction (64-lane sum, result broadcast) -------
template<int CTRL, int RMASK, bool BC>
__device__ __forceinline__ float dpp_add_step(float x) {
    int t = __builtin_amdgcn_update_dpp(0, __float_as_int(x), CTRL, RMASK, 0xf, BC);
    return x + __int_as_float(t);
}
__device__ __forceinline__ float wave_bcast_sum(float x) {
    x = dpp_add_step<0x111, 0xf, true >(x);
    x = dpp_add_step<0x112, 0xf, true >(x);
    x = dpp_add_step<0x114, 0xf, true >(x);
    x = dpp_add_step<0x118, 0xf, true >(x);
    x = dpp_add_step<0x142, 0xa, false>(x);
    x = dpp_add_step<0x143, 0xc, false>(x);
    return __int_as_float(__builtin_amdgcn_readlane(__float_as_int(x), 63));
}
// 16-lane (DPP-row) suffix sum; lane 15 of each 16-lane row holds the total.
__device__ __forceinline__ float dpp_row16_sum(float x) {
    x = dpp_add_step<0x111, 0xf, true >(x);
    x = dpp_add_step<0x112, 0xf, true >(x);
    x = dpp_add_step<0x114, 0xf, true >(x);
    x = dpp_add_step<0x118, 0xf, true >(x);
    return x;
}
__device__ __forceinline__ float rl(float v, int lane) {
    return __int_as_float(__builtin_amdgcn_readlane(__float_as_int(v), lane));
}
__device__ __forceinline__ float fast_rsq(float x) {
    float r;
    asm("v_rsq_f32 %0, %1" : "=v"(r) : "v"(x));
    return r;
}
// fp32 -> bf16 round-to-nearest-even
__device__ __forceinline__ unsigned short f2bf(float f) {
    unsigned int u = __float_as_uint(f);
    u += 0x7fffu + ((u >> 16) & 1u);
    return (unsigned short)(u >> 16);
}
// 5 simultaneous 64-lane sums via fused DPP adds (validated r7-r10).
__device__ __forceinline__ void red5_asm(float& a, float& b, float& c,
                                         float& d, float& e) {
#define R5_SHR(N)                                                              \
    asm("v_add_f32 %0, %0, %0 row_shr:" #N " row_mask:0xf bank_mask:0xf bound_ctrl:0" : "+v"(a)); \
    asm("v_add_f32 %0, %0, %0 row_shr:" #N " row_mask:0xf bank_mask:0xf bound_ctrl:0" : "+v"(b)); \
    asm("v_add_f32 %0, %0, %0 row_shr:" #N " row_mask:0xf bank_mask:0xf bound_ctrl:0" : "+v"(c)); \
    asm("v_add_f32 %0, %0, %0 row_shr:" #N " row_mask:0xf bank_mask:0xf bound_ctrl:0" : "+v"(d)); \
    asm("v_add_f32 %0, %0, %0 row_shr:" #N " row_mask:0xf bank_mask:0xf bound_ctrl:0" : "+v"(e));
#define R5_BC(N, RM)                                                           \
    asm("v_add_f32 %0, %0, %0 row_bcast:" #N " row_mask:" #RM " bank_mask:0xf" : "+v"(a)); \
    asm("v_add_f32 %0, %0, %0 row_bcast:" #N " row_mask:" #RM " bank_mask:0xf" : "+v"(b)); \
    asm("v_add_f32 %0, %0, %0 row_bcast:" #N " row_mask:" #RM " bank_mask:0xf" : "+v"(c)); \
    asm("v_add_f32 %0, %0, %0 row_bcast:" #N " row_mask:" #RM " bank_mask:0xf" : "+v"(d)); \
    asm("v_add_f32 %0, %0, %0 row_bcast:" #N " row_mask:" #RM " bank_mask:0xf" : "+v"(e));
    R5_SHR(1) R5_SHR(2) R5_SHR(4) R5_SHR(8)
    R5_BC(15, 0xa) R5_BC(31, 0xc)
#undef R5_SHR
#undef R5_BC
}

// ------ weight pre-pass: out[n][k] = bf16(in[k][n]), tiled transpose -------
__global__ __launch_bounds__(256) void wconv(
    const float* __restrict__ w0, unsigned short* __restrict__ o0,
    const float* __restrict__ w1, unsigned short* __restrict__ o1,
    const float* __restrict__ w2, unsigned short* __restrict__ o2,
    const float* __restrict__ w3, unsigned short* __restrict__ o3,
    const float* __restrict__ w4, unsigned short* __restrict__ o4,
    const float* __restrict__ w5, unsigned short* __restrict__ o5)
{
    int z = blockIdx.z;
    const float* in; unsigned short* outp; int K, N;
    if      (z == 0) { in = w0; outp = o0; K = DDIM; N = ADIM; }
    else if (z == 1) { in = w1; outp = o1; K = ADIM; N = ADIM; }
    else if (z == 2) { in = w2; outp = o2; K = ADIM; N = ADIM; }
    else if (z == 3) { in = w3; outp = o3; K = ADIM; N = ADIM; }
    else if (z == 4) { in = w4; outp = o4; K = ADIM; N = ADIM; }
    else             { in = w5; outp = o5; K = ADIM; N = DDIM; }
    int bk = blockIdx.x * 32, bn = blockIdx.y * 32;
    if (bk >= K || bn >= N) return;
    __shared__ float t[32][33];
    int tk = threadIdx.x & 31, tn = threadIdx.x >> 5;   // 32 x 8
    #pragma unroll
    for (int r = 0; r < 4; ++r)
        t[tn + r * 8][tk] = in[(size_t)(bk + tn + r * 8) * N + bn + tk];
    __syncthreads();
    #pragma unroll
    for (int r = 0; r < 4; ++r)
        outp[(size_t)(bn + tn + r * 8) * K + bk + tk] = f2bf(t[tk][tn + r * 8]);
}

// ---------------- bf16-MFMA tiled GEMM: C = act(lnA(A) @ B + bias) ---------
// r19: ping-pong LDS double-buffer, ONE barrier per k-step; next step's
// global loads issued into registers before the MFMAs (latency overlap).
// A fp32 [M][K]; Bt bf16 TRANSPOSED [N][K]. 64x64 block, 4 waves (2x2).
template<int ACT, int LAYOUT, int LNA, int STATS>
__global__ __launch_bounds__(256) void gemm_k(
    const float* __restrict__ A, const unsigned short* __restrict__ Bt,
    const float* __restrict__ bias, float* __restrict__ C,
    int M, int N, int K,
    const float2* __restrict__ lnst, const float* __restrict__ lng,
    const float* __restrict__ lnbb, float2* __restrict__ ostat)
{
    __shared__ unsigned short As[2][64][40];   // +8 pad: 80B rows, 16B-aligned
    __shared__ unsigned short Bs[2][64][40];
    __shared__ float2 lst[64];
    const int tid = threadIdx.x;
    const int bm = blockIdx.y * 64, bn = blockIdx.x * 64;
    const int lane = tid & 63, wv = tid >> 6;
    const int wr = wv >> 1, wc = wv & 1;
    const int l15 = lane & 15, l4 = lane >> 4;
    f32x4 acc[2][2] = {};

    if (LNA == 2) {
        if (tid < 64) {
            float2 s = lnst[bm + tid];
            float mu = s.x * (1.f / 192.f);
            float var = fmaf(-mu, mu, s.y * (1.f / 192.f));
            lst[tid] = make_float2(mu, rsqrtf(var + EPSLN));
        }
        __syncthreads();
    }

    const int sm = tid >> 2;          // 0..63 staging row
    const int sk = (tid & 3) * 8;     // k-segment (8 elems)

    float av[8]; uint4 bwre; int kst = 0;
    auto stage_regs = [&](int k0) {
        const float* ap = A + (size_t)(bm + sm) * K + k0 + sk;
        float4 a0 = *(const float4*)ap;
        float4 a1 = *(const float4*)(ap + 4);
        av[0] = a0.x; av[1] = a0.y; av[2] = a0.z; av[3] = a0.w;
        av[4] = a1.x; av[5] = a1.y; av[6] = a1.z; av[7] = a1.w;
        bwre = *(const uint4*)(Bt + (size_t)(bn + sm) * K + k0 + sk);
        kst = k0;
    };
    auto write_lds = [&](int buf) {
        float t[8];
        #pragma unroll
        for (int e = 0; e < 8; ++e) t[e] = av[e];
        if (LNA == 2) {
            float2 stv = lst[sm];
            #pragma unroll
            for (int e = 0; e < 8; ++e)
                t[e] = fmaf((t[e] - stv.x) * stv.y,
                            lng[kst + sk + e], lnbb[kst + sk + e]);
        }
        uint4 w;
        w.x = (unsigned)f2bf(t[0]) | ((unsigned)f2bf(t[1]) << 16);
        w.y = (unsigned)f2bf(t[2]) | ((unsigned)f2bf(t[3]) << 16);
        w.z = (unsigned)f2bf(t[4]) | ((unsigned)f2bf(t[5]) << 16);
        w.w = (unsigned)f2bf(t[6]) | ((unsigned)f2bf(t[7]) << 16);
        *(uint4*)&As[buf][sm][sk] = w;
        *(uint4*)&Bs[buf][sm][sk] = bwre;
    };

    stage_regs(0);
    write_lds(0);
    __syncthreads();
    int cur = 0;
    for (int k0 = 0; k0 < K; k0 += 32) {
        const bool more = (k0 + 32 < K);
        if (more) stage_regs(k0 + 32);     // issue loads early (latency hide)
        bf16x8 af0 = *(const bf16x8*)&As[cur][wr * 32 + l15][l4 * 8];
        bf16x8 af1 = *(const bf16x8*)&As[cur][wr * 32 + 16 + l15][l4 * 8];
        bf16x8 bf0 = *(const bf16x8*)&Bs[cur][wc * 32 + l15][l4 * 8];
        bf16x8 bf1 = *(const bf16x8*)&Bs[cur][wc * 32 + 16 + l15][l4 * 8];
        acc[0][0] = __builtin_amdgcn_mfma_f32_16x16x32_bf16(af0, bf0, acc[0][0], 0, 0, 0);
        acc[0][1] = __builtin_amdgcn_mfma_f32_16x16x32_bf16(af0, bf1, acc[0][1], 0, 0, 0);
        acc[1][0] = __builtin_amdgcn_mfma_f32_16x16x32_bf16(af1, bf0, acc[1][0], 0, 0, 0);
        acc[1][1] = __builtin_amdgcn_mfma_f32_16x16x32_bf16(af1, bf1, acc[1][1], 0, 0, 0);
        if (more) write_lds(cur ^ 1);
        __syncthreads();
        cur ^= 1;
    }

    float rs1[2][4] = {}, rs2[2][4] = {};
    #pragma unroll
    for (int rt = 0; rt < 2; ++rt) {
        #pragma unroll
        for (int ct = 0; ct < 2; ++ct) {
            #pragma unroll
            for (int r = 0; r < 4; ++r) {
                int m = bm + wr * 32 + rt * 16 + l4 * 4 + r;
                int n = bn + wc * 32 + ct * 16 + l15;
                float v = acc[rt][ct][r];
                if (bias) v += bias[n];
                if (ACT == 1) v = v / (1.f + __expf(-v));   // silu
                if (STATS) { rs1[rt][r] += v; rs2[rt][r] = fmaf(v, v, rs2[rt][r]); }
                if (LAYOUT == 0) {
                    C[(size_t)m * N + n] = v;
                } else {
                    int b  = m >> 10, s = m & 1023;
                    int hh = n >> 6,  d = n & 63;
                    C[(((size_t)b * HDIM + hh) * SDIM + s) * HD + d] = v;
                }
            }
        }
    }
    if (STATS) {
        #pragma unroll
        for (int rt = 0; rt < 2; ++rt)
            #pragma unroll
            for (int r = 0; r < 4; ++r) {
                float s1 = dpp_row16_sum(rs1[rt][r]);
                float s2 = dpp_row16_sum(rs2[rt][r]);
                if (l15 == 15) {
                    int m = bm + wr * 32 + rt * 16 + l4 * 4 + r;
                    atomicAdd(&ostat[m].x, s1);
                    atomicAdd(&ostat[m].y, s2);
                }
            }
    }
}

// ---------------- fused QKV MFMA GEMM (ping-pong, 1 barrier/step) ----------
__global__ __launch_bounds__(256) void gemm_qkv(
    const float* __restrict__ A, const unsigned short* __restrict__ BTq,
    const unsigned short* __restrict__ BTk, const unsigned short* __restrict__ BTv,
    float* __restrict__ Cbase)
{
    const unsigned short* Bt = (blockIdx.z == 0) ? BTq
                              : (blockIdx.z == 1) ? BTk : BTv;
    float* C = Cbase + (size_t)blockIdx.z * ((size_t)MROWS * ADIM);
    __shared__ unsigned short As[2][64][40];
    __shared__ unsigned short Bs[2][64][40];
    const int tid = threadIdx.x;
    const int bm = blockIdx.y * 64, bn = blockIdx.x * 64;
    const int lane = tid & 63, wv = tid >> 6;
    const int wr = wv >> 1, wc = wv & 1;
    const int l15 = lane & 15, l4 = lane >> 4;
    f32x4 acc[2][2] = {};

    const int sm = tid >> 2;
    const int sk = (tid & 3) * 8;

    float av[8]; uint4 bwre;
    auto stage_regs = [&](int k0) {
        const float* ap = A + (size_t)(bm + sm) * ADIM + k0 + sk;
        float4 a0 = *(const float4*)ap;
        float4 a1 = *(const float4*)(ap + 4);
        av[0] = a0.x; av[1] = a0.y; av[2] = a0.z; av[3] = a0.w;
        av[4] = a1.x; av[5] = a1.y; av[6] = a1.z; av[7] = a1.w;
        bwre = *(const uint4*)(Bt + (size_t)(bn + sm) * ADIM + k0 + sk);
    };
    auto write_lds = [&](int buf) {
        uint4 w;
        w.x = (unsigned)f2bf(av[0]) | ((unsigned)f2bf(av[1]) << 16);
        w.y = (unsigned)f2bf(av[2]) | ((unsigned)f2bf(av[3]) << 16);
        w.z = (unsigned)f2bf(av[4]) | ((unsigned)f2bf(av[5]) << 16);
        w.w = (unsigned)f2bf(av[6]) | ((unsigned)f2bf(av[7]) << 16);
        *(uint4*)&As[buf][sm][sk] = w;
        *(uint4*)&Bs[buf][sm][sk] = bwre;
    };

    stage_regs(0);
    write_lds(0);
    __syncthreads();
    int cur = 0;
    for (int k0 = 0; k0 < ADIM; k0 += 32) {
        const bool more = (k0 + 32 < ADIM);
        if (more) stage_regs(k0 + 32);
        bf16x8 af0 = *(const bf16x8*)&As[cur][wr * 32 + l15][l4 * 8];
        bf16x8 af1 = *(const bf16x8*)&As[cur][wr * 32 + 16 + l15][l4 * 8];
        bf16x8 bf0 = *(const bf16x8*)&Bs[cur][wc * 32 + l15][l4 * 8];
        bf16x8 bf1 = *(const bf16x8*)&Bs[cur][wc * 32 + 16 + l15][l4 * 8];
        acc[0][0] = __builtin_amdgcn_mfma_f32_16x16x32_bf16(af0, bf0, acc[0][0], 0, 0, 0);
        acc[0][1] = __builtin_amdgcn_mfma_f32_16x16x32_bf16(af0, bf1, acc[0][1], 0, 0, 0);
        acc[1][0] = __builtin_amdgcn_mfma_f32_16x16x32_bf16(af1, bf0, acc[1][0], 0, 0, 0);
        acc[1][1] = __builtin_amdgcn_mfma_f32_16x16x32_bf16(af1, bf1, acc[1][1], 0, 0, 0);
        if (more) write_lds(cur ^ 1);
        __syncthreads();
        cur ^= 1;
    }

    #pragma unroll
    for (int rt = 0; rt < 2; ++rt)
        #pragma unroll
        for (int ct = 0; ct < 2; ++ct)
            #pragma unroll
            for (int r = 0; r < 4; ++r) {
                int m = bm + wr * 32 + rt * 16 + l4 * 4 + r;
                int n = bn + wc * 32 + ct * 16 + l15;
                int b  = m >> 10, s = m & 1023;
                int hh = n >> 6,  d = n & 63;
                C[(((size_t)b * HDIM + hh) * SDIM + s) * HD + d] = acc[rt][ct][r];
            }
}

// -- pre: A=[k.k+1], B=[q.k+1], a-vectors (into vb), r6, eta, stat-zero ------
// r19: Kc/Qc padded to [32][68] (272B rows, 16B-aligned) -> float4 Gram loop.
__global__ __launch_bounds__(256) void ab_kernel(
    const float* __restrict__ qb, const float* __restrict__ kb,
    float* __restrict__ vb,            // in: v; out: a = (bw-(v-k))*gw
    const float* __restrict__ ttt_g, const float* __restrict__ ttt_b,
    float* __restrict__ Ab, float* __restrict__ Bb,
    float* __restrict__ r6b,
    const float* __restrict__ h, const float* __restrict__ lr_w,
    const float* __restrict__ lr_b, float* __restrict__ etab,
    float4* __restrict__ stz)
{
    int bh = blockIdx.x >> 5, c = blockIdx.x & 31, cs = c * 32;
    int hh = bh % HDIM, b = bh / HDIM;
    __shared__ float Kc[32][68], Qc[32][68], Vc[32][65];
    __shared__ float ep[32][8];

    if (blockIdx.x < 16) {   // zero 4096 float4 = both stat buffers
        float4 z4; z4.x = z4.y = z4.z = z4.w = 0.f;
        stz[blockIdx.x * 256 + threadIdx.x] = z4;
    }

    // eta partial: 8 threads per token row, 24 h-elems each (coalesced)
    {
        int rg = threadIdx.x >> 3, sl = threadIdx.x & 7;
        const float* hrow = h + ((size_t)b * SDIM + cs + rg) * ADIM + sl * 24;
        float esum = 0.f;
        #pragma unroll
        for (int jj = 0; jj < 24; ++jj)
            esum = fmaf(hrow[jj], lr_w[(sl * 24 + jj) * 3 + hh], esum);
        ep[rg][sl] = esum;
    }

    for (int i = threadIdx.x; i < 2048; i += 256) {
        int t = i >> 6, j = i & 63;
        Kc[t][j] = kb[((size_t)bh * SDIM + cs + t) * HD + j];
        Qc[t][j] = qb[((size_t)bh * SDIM + cs + t) * HD + j];
        Vc[t][j] = vb[((size_t)bh * SDIM + cs + t) * HD + j];
    }
    __syncthreads();

    if (threadIdx.x < 32) {   // finalize eta for this block's 32 tokens
        int t = threadIdx.x;
        float acc = ((ep[t][0] + ep[t][1]) + (ep[t][2] + ep[t][3]))
                  + ((ep[t][4] + ep[t][5]) + (ep[t][6] + ep[t][7]))
                  + lr_b[hh];
        float e = 1.f / (1.f + __expf(-acc)) * (1.f / 64.f);
        etab[(size_t)bh * SDIM + cs + t] = e;
    }

    size_t base = ((size_t)(bh * NCHUNK + c)) * 1024;
    for (int e = threadIdx.x; e < 1024; e += 256) {
        int t = e >> 5, s = e & 31;
        float a = 1.f, bv = 1.f;
        #pragma unroll
        for (int j4 = 0; j4 < 16; ++j4) {
            float4 ks = *(const float4*)&Kc[s][j4 * 4];
            float4 kt = *(const float4*)&Kc[t][j4 * 4];
            float4 qt = *(const float4*)&Qc[t][j4 * 4];
            a  = fmaf(kt.x, ks.x, a);  a  = fmaf(kt.y, ks.y, a);
            a  = fmaf(kt.z, ks.z, a);  a  = fmaf(kt.w, ks.w, a);
            bv = fmaf(qt.x, ks.x, bv); bv = fmaf(qt.y, ks.y, bv);
            bv = fmaf(qt.z, ks.z, bv); bv = fmaf(qt.w, ks.w, bv);
        }
        Ab[base + e] = a;
        Bb[base + e] = bv;
    }
    for (int i = threadIdx.x; i < 2048; i += 256) {
        int t = i >> 6, j = i & 63;
        float gwv = ttt_g[hh * 64 + j], bwv = ttt_b[hh * 64 + j];
        float av = fmaf(-(Vc[t][j] - Kc[t][j]), gwv, bwv * gwv);
        Vc[t][j] = av;
        vb[((size_t)bh * SDIM + cs + t) * HD + j] = av;
    }
    __syncthreads();
    if (threadIdx.x < 32) {
        int t = threadIdx.x;
        float acc = 0.f;
        #pragma unroll
        for (int j = 0; j < 64; ++j) acc += Vc[t][j];
        r6b[(size_t)bh * SDIM + cs + t] = acc;
    }
}

// ---------------- staging helper (global -> LDS, float4) -------------------
__device__ __forceinline__ void stage_chunk(
    int pp, int cc, int bh, int idx, int nth,
    const float* __restrict__ kbuf, const float* __restrict__ abuf,
    const float* __restrict__ Ab, const float* __restrict__ etab,
    const float* __restrict__ r6b,
    float4* K4, float4* a4, float4* A4, float2* er6)
{
    const float4* kg = (const float4*)(kbuf + ((size_t)bh * SDIM + cc * 32) * HD);
    const float4* ag = (const float4*)(abuf + ((size_t)bh * SDIM + cc * 32) * HD);
    const float4* Ag = (const float4*)(Ab + ((size_t)(bh * NCHUNK + cc)) * 1024);
    for (int i = idx; i < 512; i += nth) K4[pp * 512 + i] = kg[i];
    for (int i = idx; i < 512; i += nth) a4[pp * 512 + i] = ag[i];
    for (int i = idx; i < 256; i += nth) A4[pp * 256 + i] = Ag[i];
    for (int i = idx; i < 32; i += nth)
        er6[pp * 32 + i] = make_float2(
            etab[(size_t)bh * SDIM + cc * 32 + i] * (1.f / 64.f),
            r6b[(size_t)bh * SDIM + cc * 32 + i]);
}

// ---------------- the sequential TTT scan (12 blocks) — r16 verbatim -------
__global__ __launch_bounds__(256, 1) void ttt_scan(
    const float* __restrict__ kbuf, const float* __restrict__ abuf,
    const float* __restrict__ etab, const float* __restrict__ Ab,
    const float* __restrict__ r6b,
    const float* __restrict__ W1,   const float* __restrict__ b1,
    const float* __restrict__ ttt_g, const float* __restrict__ ttt_b,
    float* __restrict__ Gbuf, float* __restrict__ W0save, float* __restrict__ b0save)
{
    const int bh = blockIdx.x, hh = bh % HDIM;
    const int tid = threadIdx.x, lane = tid & 63;
    const int wv = tid >> 6;
    __shared__ float  Zp[4][16][64];   // 16 KB (slice 0 unused)
    __shared__ float4 K4s[2 * 512];    // 16 KB: K double-buffered
    __shared__ float4 a4s[2 * 512];    // 16 KB: a double-buffered
    __shared__ float4 A4s[2 * 256];    //  8 KB: A double-buffered
    __shared__ float2 er6s[2 * 32];    // 512 B
    __shared__ float  Gl[16][64];      //  4 KB: per-token eta*g (sub-chunk)

    float Wreg[16];
    #pragma unroll
    for (int r = 0; r < 16; ++r)
        Wreg[r] = W1[hh * 4096 + (wv * 16 + r) * 64 + lane];
    float breg = b1[hh * 64 + lane];
    const float gw = ttt_g[hh * 64 + lane];
    const float bw = ttt_b[hh * 64 + lane];
    const float w3 = gw * gw;
    (void)bw;
    const float Cg2 = wave_bcast_sum(w3);
    const float* a_f = (const float*)a4s;

    stage_chunk(0, 0, bh, tid, 256, kbuf, abuf, Ab, etab, r6b,
                K4s, a4s, A4s, er6s);
    __syncthreads();

    for (int c = 0; c < NCHUNK; ++c) {
        const int cs = c * 32;
        const int p = c & 1;

        {
            float* Wd = W0save + ((size_t)(bh * NCHUNK + c)) * 4096
                        + (wv * 16) * 64 + lane;
            #pragma unroll
            for (int r = 0; r < 16; ++r) Wd[r * 64] = Wreg[r];
            if (tid < 64) b0save[(bh * NCHUNK + c) * 64 + tid] = breg;
        }

        #pragma unroll
        for (int h = 0; h < 2; ++h) {
            const int h16 = h * 16, h4 = h * 4;

            // ---- P1 (all waves): Z0 partials for tokens [h16, h16+16) ----
            float Zt[16];
            #pragma unroll
            for (int i = 0; i < 16; ++i) {
                const int t = h16 + i;
                float zt = 0.f;
                #pragma unroll
                for (int r4 = 0; r4 < 4; ++r4) {
                    const float4 kv = K4s[p * 512 + t * 16 + wv * 4 + r4];
                    zt = fmaf(kv.x, Wreg[r4 * 4 + 0], zt);
                    zt = fmaf(kv.y, Wreg[r4 * 4 + 1], zt);
                    zt = fmaf(kv.z, Wreg[r4 * 4 + 2], zt);
                    zt = fmaf(kv.w, Wreg[r4 * 4 + 3], zt);
                }
                Zt[i] = zt;
            }
            if (wv != 0) {
                #pragma unroll
                for (int i = 0; i < 16; ++i)
                    Zp[wv][i][lane] = (wv == 1) ? Zt[i] + breg : Zt[i];
            }
            __syncthreads();   // (A) Zp ready; buffer p staged

            // ---- P2: wave 0 serial; waves 1-3 stage next chunk (h==0) ----
            if (wv == 0) {
                __builtin_amdgcn_s_setprio(1);
                float Z[16];
                #pragma unroll
                for (int i = 0; i < 16; ++i) {
                    float q1 = Zp[1][i][lane], q2 = Zp[2][i][lane],
                          q3 = Zp[3][i][lane];
                    Z[i] = ((Zt[i] + q1) + (q2 + q3));
                }
                float4 avA[4], avB[4];
                float aA, aB; float2 erA, erB;
                #pragma unroll
                for (int q = 0; q < 4; ++q)
                    avA[q] = A4s[p * 256 + h16 * 8 + h4 + q];
                aA  = a_f[p * 2048 + h16 * 64 + lane];
                erA = er6s[p * 32 + h16];
#define TOK(I, avC, aC, erC, avN, aN, erN)                                     \
    {                                                                          \
        if ((I) < 15) {                                                        \
            _Pragma("unroll")                                                  \
            for (int q = ((I) + 2) >> 2; q < 4; ++q)                           \
                avN[q] = A4s[p * 256 + (h16 + (I) + 1) * 8 + h4 + q];          \
            aN  = a_f[p * 2048 + (h16 + (I) + 1) * 64 + lane];                 \
            erN = er6s[p * 32 + h16 + (I) + 1];                                \
        }                                                                      \
        float z  = Z[I];                                                       \
        float a  = aC;                                                         \
        float zg = z * w3;                                                     \
        float x1 = z, x2 = z * z, x3 = zg, x4 = zg * z, x5 = z * a;            \
        red5_asm(x1, x2, x3, x4, x5);                                          \
        float r1 = rl(x1, 63), r2 = rl(x2, 63), r3 = rl(x3, 63);               \
        float r4 = rl(x4, 63), r5 = rl(x5, 63);                                \
        float r6t = (erC).y;                                                   \
        float mu   = r1 * (1.f / 64.f);                                        \
        float var  = fmaf(-mu, mu, r2 * (1.f / 64.f));                         \
        float rstd = fast_rsq(var + EPSLN);                                    \
        float mc   = mu * Cg2;                                                 \
        float sgxh = fmaf(rstd, r3 - mc, r6t);                                 \
        float t4v  = fmaf(mu, mc, fmaf(-2.f * mu, r3, r4));                    \
        float sgz  = fmaf(rstd * rstd, t4v, rstd * (r5 - mu * r6t));           \
        float zh   = (z - mu) * rstd;                                          \
        float gxh  = fmaf(zh, w3, a);                                          \
        float ge   = (fmaf(64.f, gxh, -sgxh) - zh * sgz) * (rstd * (erC).x);   \
        Gl[I][lane] = ge;                                                      \
        _Pragma("unroll")                                                      \
        for (int u = (I) + 1; u < 16; ++u) {                                   \
            const float4 c4 = avC[(u) >> 2]; const int m4 = (u) & 3;           \
            float Atu = (m4 == 0) ? c4.x : (m4 == 1) ? c4.y                    \
                      : (m4 == 2) ? c4.z : c4.w;                               \
            Z[u] = fmaf(-Atu, ge, Z[u]);                                       \
        }                                                                      \
    }
                #pragma unroll
                for (int tp = 0; tp < 8; ++tp) {
                    TOK(2 * tp,     avA, aA, erA, avB, aB, erB)
                    TOK(2 * tp + 1, avB, aB, erB, avA, aA, erA)
                }
#undef TOK
                __builtin_amdgcn_s_setprio(0);
            } else if (h == 0 && c < NCHUNK - 1) {
                stage_chunk(p ^ 1, c + 1, bh, tid - 64, 192,
                            kbuf, abuf, Ab, etab, r6b, K4s, a4s, A4s, er6s);
            }
            __syncthreads();   // (B) Gl ready; staging (h==0) done

            // ---- P3 (all waves): W -= K^T@G ; b -= colsum(G); Gbuf -------
            float btot = 0.f;
            #pragma unroll
            for (int s = 0; s < 16; ++s) {
                float gd = Gl[s][lane];
                btot += gd;
                #pragma unroll
                for (int r4 = 0; r4 < 4; ++r4) {
                    const float4 kv = K4s[p * 512 + (h16 + s) * 16 + wv * 4 + r4];
                    Wreg[r4 * 4 + 0] = fmaf(-kv.x, gd, Wreg[r4 * 4 + 0]);
                    Wreg[r4 * 4 + 1] = fmaf(-kv.y, gd, Wreg[r4 * 4 + 1]);
                    Wreg[r4 * 4 + 2] = fmaf(-kv.z, gd, Wreg[r4 * 4 + 2]);
                    Wreg[r4 * 4 + 3] = fmaf(-kv.w, gd, Wreg[r4 * 4 + 3]);
                }
            }
            breg -= btot;
            {
                float* gb = Gbuf + ((size_t)bh * SDIM + cs + h16) * HD + lane;
                #pragma unroll
                for (int r = 0; r < 4; ++r)
                    gb[(wv * 4 + r) * HD] = Gl[wv * 4 + r][lane];
            }
        }
    }
}

// ---------------- post: Zq = Qc@W0 + b0 - tril(B)@G ; ys = q + ln(Zq) ------
__global__ __launch_bounds__(256) void post_kernel(
    const float* __restrict__ qbuf, const float* __restrict__ Bb,
    const float* __restrict__ Gbuf, const float* __restrict__ W0save,
    const float* __restrict__ b0save,
    const float* __restrict__ ttt_g, const float* __restrict__ ttt_b,
    float* __restrict__ ys, float2* __restrict__ ystat)
{
    const int bh = blockIdx.x >> 5, c = blockIdx.x & 31, cs = c * 32;
    const int b = bh / HDIM, hh = bh % HDIM;
    const int tid = threadIdx.x, lane = tid & 63, wave = tid >> 6;
    __shared__ float Qc[32][65];
    __shared__ float W0l[64][65];
    __shared__ float Gl[32][64];
    for (int i = tid; i < 2048; i += 256) {
        int t = i >> 6, j = i & 63;
        Qc[t][j] = qbuf[((size_t)bh * SDIM + cs + t) * HD + j];
        Gl[t][j] = Gbuf[((size_t)bh * SDIM + cs + t) * HD + j];
    }
    for (int i = tid; i < 4096; i += 256)
        W0l[i >> 6][i & 63] = W0save[((size_t)(bh * NCHUNK + c)) * 4096 + i];
    __syncthreads();

    const float bb0 = b0save[(bh * NCHUNK + c) * 64 + lane];
    const float gw = ttt_g[hh * 64 + lane], bw = ttt_b[hh * 64 + lane];
    float acc[8];
    #pragma unroll
    for (int r = 0; r < 8; ++r) acc[r] = bb0;
    for (int j = 0; j < 64; ++j) {
        float w0 = W0l[j][lane];
        #pragma unroll
        for (int r = 0; r < 8; ++r)
            acc[r] = fmaf(Qc[wave * 8 + r][j], w0, acc[r]);
    }
    float Breg[8];
    size_t bbase = ((size_t)(bh * NCHUNK + c)) * 1024;
    #pragma unroll
    for (int r = 0; r < 8; ++r)
        Breg[r] = Bb[bbase + (wave * 8 + r) * 32 + (lane & 31)];
    #pragma unroll
    for (int s = 0; s < 32; ++s) {
        float gd = Gl[s][lane];
        #pragma unroll
        for (int r = 0; r < 8; ++r) {
            int t = wave * 8 + r;
            float Bts = rl(Breg[r], s);
            acc[r] = (s <= t) ? fmaf(-Bts, gd, acc[r]) : acc[r];
        }
    }
    #pragma unroll
    for (int r = 0; r < 8; ++r) {
        int t = wave * 8 + r;
        float s1 = wave_bcast_sum(acc[r]);
        float s2 = wave_bcast_sum(acc[r] * acc[r]);
        float mu = s1 * (1.f / 64.f);
        float var = s2 * (1.f / 64.f) - mu * mu;
        float rstd = rsqrtf(var + EPSLN);
        float zh = (acc[r] - mu) * rstd;
        float val = zh * gw + bw + Qc[t][lane];
        ys[((size_t)(b * SDIM) + cs + t) * ADIM + hh * HD + lane] = val;
        float t1 = wave_bcast_sum(val);
        float t2 = wave_bcast_sum(val * val);
        if (lane == 0) {
            atomicAdd(&ystat[(size_t)b * SDIM + cs + t].x, t1);
            atomicAdd(&ystat[(size_t)b * SDIM + cs + t].y, t2);
        }
    }
}

// ---------------- launch ---------------------------------------------------
extern "C" void kernel_launch(void* const* d_in, const int* in_sizes, int n_in,
                              void* d_out, int out_size, void* d_ws, size_t ws_size,
                              hipStream_t stream)
{
    const float* x      = (const float*)d_in[0];
    const float* W_down = (const float*)d_in[1];
    const float* b_down = (const float*)d_in[2];
    const float* Wq     = (const float*)d_in[3];
    const float* Wk     = (const float*)d_in[4];
    const float* Wv     = (const float*)d_in[5];
    const float* Wo     = (const float*)d_in[6];
    const float* W1     = (const float*)d_in[7];
    const float* b1     = (const float*)d_in[8];
    const float* ttt_g  = (const float*)d_in[9];
    const float* ttt_b  = (const float*)d_in[10];
    const float* lr_w   = (const float*)d_in[11];
    const float* lr_b   = (const float*)d_in[12];
    const float* post_g = (const float*)d_in[13];
    const float* post_b = (const float*)d_in[14];
    const float* norm_g = (const float*)d_in[15];
    const float* norm_b = (const float*)d_in[16];
    const float* W_up   = (const float*)d_in[17];
    const float* b_up   = (const float*)d_in[18];
    float* out = (float*)d_out;

    float* ws = (float*)d_ws;
    const size_t SZ = (size_t)MROWS * ADIM;      // 786432
    float* h    = ws;                // [4096][192]
    float* qb   = ws + SZ;           // [12][1024][64]
    float* kb   = ws + 2 * SZ;
    float* vb   = ws + 3 * SZ;       // after ab_kernel: a-vectors
    float* Gb   = ws + 4 * SZ;
    float* etab = ws + 5 * SZ;                       // 12288
    float* Ab   = etab + 12288;                      // 393216
    float* Bb   = Ab + 393216;                       // 393216
    float* W0s  = Bb + 393216;                       // 1572864
    float* b0s  = W0s + 1572864;                     // 24576
    float* r6b  = b0s + 24576;                       // 12288
    float2* ystat = (float2*)(r6b + 12288);          // 4096 float2 (Sum,SumSq)
    float2* tstat = ystat + 4096;                    // 4096 float2
    unsigned short* WdT = (unsigned short*)(tstat + 4096);  // [192][768] bf16
    unsigned short* WqT = WdT + 147456;              // [192][192]
    unsigned short* WkT = WqT + 36864;
    unsigned short* WvT = WkT + 36864;
    unsigned short* WoT = WvT + 36864;
    unsigned short* WuT = WoT + 36864;               // [768][192]
    // aliases (lifetime-disjoint)
    float* ysb  = h;    // post_kernel output (h dead after ab's eta)
    float* tbuf = qb;   // ln(ys)@Wo (qb dead after post_kernel)

    // 0) weights -> bf16 transposed (once per invocation, ~2us)
    wconv<<<dim3(24, 24, 6), 256, 0, stream>>>(
        W_down, WdT, Wq, WqT, Wk, WkT, Wv, WvT, Wo, WoT, W_up, WuT);
    // 1) h = silu(x @ W_down + b_down)   [MFMA, ping-pong]
    gemm_k<1, 0, 0, 0><<<dim3(ADIM / 64, MROWS / 64), 256, 0, stream>>>(
        x, WdT, b_down, h, MROWS, ADIM, DDIM,
        nullptr, nullptr, nullptr, nullptr);
    // 2) q,k,v in ONE launch   [MFMA, ping-pong]
    gemm_qkv<<<dim3(ADIM / 64, MROWS / 64, 3), 256, 0, stream>>>(
        h, WqT, WkT, WvT, qb);
    // 3) chunk coefficients + a-vectors + r6 + eta + stat-buffer zero
    ab_kernel<<<BDIM * HDIM * NCHUNK, 256, 0, stream>>>(
        qb, kb, vb, ttt_g, ttt_b, Ab, Bb, r6b,
        h, lr_w, lr_b, etab, (float4*)ystat);
    // 4) sequential scan (r16 structure, proven)
    ttt_scan<<<BDIM * HDIM, 256, 0, stream>>>(
        kb, vb, etab, Ab, r6b, W1, b1, ttt_g, ttt_b, Gb, W0s, b0s);
    // 5) outputs ys = q + ln(Zq); accumulates ystat
    post_kernel<<<BDIM * HDIM * NCHUNK, 256, 0, stream>>>(
        qb, Bb, Gb, W0s, b0s, ttt_g, ttt_b, ysb, ystat);
    // 6) t = ln(ys) @ Wo  [MFMA; LN from ystat; accumulates tstat]
    gemm_k<0, 0, 2, 1><<<dim3(ADIM / 64, MROWS / 64), 256, 0, stream>>>(
        ysb, WoT, nullptr, tbuf, MROWS, ADIM, ADIM,
        ystat, post_g, post_b, tstat);
    // 7) out = ln(t) @ W_up + b_up  [MFMA; LN from tstat]
    gemm_k<0, 0, 2, 0><<<dim3(DDIM / 64, MROWS / 64), 256, 0, stream>>>(
        tbuf, WuT, b_up, out, MROWS, DDIM, ADIM,
        tstat, norm_g, norm_b, nullptr);
}